// Round 6
// baseline (762.960 us; speedup 1.0000x reference)
//
#include <hip/hip_runtime.h>

// ---------------------------------------------------------------------------
// DeepProteinClassifier: x[32,1024,960] fp32, mask[32,1024] i32 ->
//   fused QKV proj -> fused attention (scores+softmax) -> PV GEMM (bf16 ctx)
//   -> +x, LN -> masked mean pool -> MLP -> [32,10] f32
// gemmY: BM=192/BN=128/BK=64, 4 waves, per-wave 96x64 (38 FLOP/LDS-byte),
// 80KB dbuf LDS -> 2 blocks/CU, counted-vmcnt pipeline.
// ---------------------------------------------------------------------------

#define DEVINL __device__ __forceinline__

typedef __attribute__((ext_vector_type(8))) short bf16x8;
typedef __attribute__((ext_vector_type(4))) float f32x4;
typedef __attribute__((ext_vector_type(4))) unsigned short u16x4;

DEVINL unsigned short f2bf(float f) {
  unsigned int u = __float_as_uint(f);
  u += 0x7FFFu + ((u >> 16) & 1u);  // round-to-nearest-even
  return (unsigned short)(u >> 16);
}

DEVINL float bf2f(unsigned short h) { return __uint_as_float(((unsigned int)h) << 16); }

DEVINL void gload_lds16(const void* g, void* l) {
  __builtin_amdgcn_global_load_lds((const __attribute__((address_space(1))) unsigned int*)g,
                                   (__attribute__((address_space(3))) unsigned int*)l,
                                   16, 0, 0);
}

#define MFMA16(a, b, c) __builtin_amdgcn_mfma_f32_16x16x32_bf16((a), (b), (c), 0, 0, 0)

// ---------------------------------------------------------------------------
// Build Wqkv [3072][1024] bf16 (rows 0..959 Wq*scale, 960..1919 Wk,
// 1920..2879 Wv; cols 960..1023 zero) and biasQKV[2880] f32.
// ---------------------------------------------------------------------------
__global__ __launch_bounds__(256) void cast_wqkv(
    const float* __restrict__ Wq, const float* __restrict__ Wk, const float* __restrict__ Wv,
    const float* __restrict__ bq, const float* __restrict__ bk, const float* __restrict__ bv,
    unsigned short* __restrict__ Wqkv, float* __restrict__ biasQ, float scaleQ) {
  const int r = blockIdx.x, t = threadIdx.x;
  const int seg = (r >= 1920) ? 2 : (r >= 960 ? 1 : 0);
  const int sr = r - seg * 960;
  const float* W = (seg == 0) ? Wq : (seg == 1) ? Wk : Wv;
  const float sc = (seg == 0) ? scaleQ : 1.0f;
  if (t < 240) {
    f32x4 v = *(const f32x4*)(W + (size_t)sr * 960 + t * 4);
    u16x4 o;
    o[0] = f2bf(v[0] * sc); o[1] = f2bf(v[1] * sc);
    o[2] = f2bf(v[2] * sc); o[3] = f2bf(v[3] * sc);
    *(u16x4*)(Wqkv + (size_t)r * 1024 + t * 4) = o;
  } else {
    u16x4 z = {};
    *(u16x4*)(Wqkv + (size_t)r * 1024 + 960 + (t - 240) * 4) = z;
  }
  if (t == 0) {
    const float* bb = (seg == 0) ? bq : (seg == 1) ? bk : bv;
    biasQ[r] = bb[sr] * sc;
  }
}

// ---------------------------------------------------------------------------
// cast x [32768][960] f32 -> xb [32768][1024] bf16 (cols 960.. zero).
// ---------------------------------------------------------------------------
__global__ __launch_bounds__(256) void cast_x(
    const float* __restrict__ x, unsigned short* __restrict__ xb) {
  const int row = blockIdx.x * 4 + (threadIdx.x >> 6);
  const int l = threadIdx.x & 63;
  unsigned short* o = xb + (size_t)row * 1024 + l * 16;
  if (l < 60) {
    const float* g = x + (size_t)row * 960 + l * 16;
    f32x4 v0 = *(const f32x4*)(g);
    f32x4 v1 = *(const f32x4*)(g + 4);
    f32x4 v2 = *(const f32x4*)(g + 8);
    f32x4 v3 = *(const f32x4*)(g + 12);
    bf16x8 o0, o1;
    o0[0] = (short)f2bf(v0[0]); o0[1] = (short)f2bf(v0[1]);
    o0[2] = (short)f2bf(v0[2]); o0[3] = (short)f2bf(v0[3]);
    o0[4] = (short)f2bf(v1[0]); o0[5] = (short)f2bf(v1[1]);
    o0[6] = (short)f2bf(v1[2]); o0[7] = (short)f2bf(v1[3]);
    o1[0] = (short)f2bf(v2[0]); o1[1] = (short)f2bf(v2[1]);
    o1[2] = (short)f2bf(v2[2]); o1[3] = (short)f2bf(v2[3]);
    o1[4] = (short)f2bf(v3[0]); o1[5] = (short)f2bf(v3[1]);
    o1[6] = (short)f2bf(v3[2]); o1[7] = (short)f2bf(v3[3]);
    *(bf16x8*)(o) = o0;
    *(bf16x8*)(o + 8) = o1;
  } else {
    bf16x8 z = {};
    *(bf16x8*)(o) = z;
    *(bf16x8*)(o + 8) = z;
  }
}

// ---------------------------------------------------------------------------
// gemmY: 192x128 NT GEMM tile, BK=64, 4 waves (2M x 2N), per-wave 96x64
// (acc[6][4]); LDS As[2][192*64] + Bs[2][128*64] = 80 KB -> 2 blocks/CU.
// Counted-vmcnt: STAGE(t+1) [10 gloads/thread], vmcnt(10), s_barrier,
// compute(t) [20 ds_read_b128 + 48 MFMA], s_barrier. Source-side (row&7)
// 16B-slot XOR swizzle (measured 0 bank conflicts at BK=64).
// MODE 1: QKV epilogue (bf16 +bias -> Qb/Kb/Vt-transposed).
// MODE 2: bf16 out (PV -> ctx bf16).
// m204 bijective XCD swizzle over flat grid; n-tile fastest.
// ---------------------------------------------------------------------------
template <int MODE>
__global__ __launch_bounds__(256, 2) void gemmY(
    const unsigned short* __restrict__ Ap, const unsigned short* __restrict__ Bp,
    int lda, int ldb, const float* __restrict__ bias,
    unsigned short* __restrict__ outC, unsigned short* __restrict__ outQ,
    unsigned short* __restrict__ outK, unsigned short* __restrict__ outV,
    int mTiles, int nTiles, int nkt, int mMax, int ncols, int ldo,
    size_t aStride, size_t bStride, size_t oStride) {
  __shared__ unsigned short As[2][192 * 64];
  __shared__ unsigned short Bs[2][128 * 64];
  const int t = threadIdx.x, l = t & 63, w = t >> 6;
  const int wr = w >> 1, wc = w & 1;
  const int lq = l & 15, lh = l >> 4;

  // bijective XCD-chunked swizzle (m204): works for any nwg
  const int nwg = (int)gridDim.x;
  const int flat = (int)blockIdx.x;
  const int q8 = nwg >> 3, r8 = nwg & 7, xcd = flat & 7;
  const int wgid = (xcd < r8 ? xcd * (q8 + 1) : r8 * (q8 + 1) + (xcd - r8) * q8) + (flat >> 3);
  const int pt = mTiles * nTiles;
  const int zb = wgid / pt;
  const int rm = wgid - zb * pt;
  const int mi = rm / nTiles;
  const int m0 = mi * 192;
  const int n0 = (rm - mi * nTiles) * 128;

  const unsigned short* A = Ap + (size_t)zb * aStride + (size_t)m0 * lda;
  const unsigned short* B = Bp + (size_t)zb * bStride + (size_t)n0 * ldb;

  // stage: A 6 passes x 32 rows, B 4 passes x 32 rows; 10 gloads/thread
#define STAGEY(D0, BB)                                                        \
  {                                                                           \
    _Pragma("unroll") for (int p_ = 0; p_ < 6; ++p_) {                        \
      const int r_ = p_ * 32 + w * 8 + (l >> 3);                              \
      const int sg_ = (l & 7) ^ (r_ & 7);                                     \
      gload_lds16(A + (size_t)r_ * lda + (D0) + sg_ * 8,                      \
                  (char*)&As[BB][(size_t)(p_ * 32 + w * 8) * 64]);            \
    }                                                                         \
    _Pragma("unroll") for (int p_ = 0; p_ < 4; ++p_) {                        \
      const int r_ = p_ * 32 + w * 8 + (l >> 3);                              \
      const int sg_ = (l & 7) ^ (r_ & 7);                                     \
      gload_lds16(B + (size_t)r_ * ldb + (D0) + sg_ * 8,                      \
                  (char*)&Bs[BB][(size_t)(p_ * 32 + w * 8) * 64]);            \
    }                                                                         \
  }

  f32x4 acc[6][4] = {};
  STAGEY(0, 0);
  int buf = 0;
  for (int kt = 0; kt < nkt; ++kt) {
    if (kt + 1 < nkt) {
      STAGEY((kt + 1) * 64, buf ^ 1);
      asm volatile("s_waitcnt vmcnt(10)" ::: "memory");  // tile kt landed; kt+1 in flight
    } else {
      asm volatile("s_waitcnt vmcnt(0)" ::: "memory");
    }
    __builtin_amdgcn_sched_barrier(0);
    __builtin_amdgcn_s_barrier();
#pragma unroll
    for (int kk = 0; kk < 2; ++kk) {
      bf16x8 aF[6], bF[4];
#pragma unroll
      for (int i = 0; i < 6; ++i) {
        const int rowA = 96 * wr + 16 * i + lq;
        aF[i] = *(const bf16x8*)&As[buf][(size_t)rowA * 64 +
                                         (size_t)(((kk << 2) | lh) ^ (rowA & 7)) * 8];
      }
#pragma unroll
      for (int j = 0; j < 4; ++j) {
        const int rowB = 64 * wc + 16 * j + lq;
        bF[j] = *(const bf16x8*)&Bs[buf][(size_t)rowB * 64 +
                                         (size_t)(((kk << 2) | lh) ^ (rowB & 7)) * 8];
      }
#pragma unroll
      for (int i = 0; i < 6; ++i)
#pragma unroll
        for (int j = 0; j < 4; ++j) acc[i][j] = MFMA16(aF[i], bF[j], acc[i][j]);
    }
    __builtin_amdgcn_s_barrier();
    buf ^= 1;
  }
#undef STAGEY

  // epilogue: C/D layout col = lane&15, row = (lane>>4)*4 + reg
  if (MODE == 2) {  // bf16 ctx out
#pragma unroll
    for (int j = 0; j < 4; ++j) {
      const int col = n0 + 64 * wc + 16 * j + lq;
      if (col >= ncols) continue;
#pragma unroll
      for (int i = 0; i < 6; ++i)
#pragma unroll
        for (int r = 0; r < 4; ++r) {
          const int row = m0 + 96 * wr + 16 * i + 4 * lh + r;
          if (row < mMax)
            outC[(size_t)zb * oStride + (size_t)row * ldo + col] = f2bf(acc[i][j][r]);
        }
    }
  } else {  // MODE 1: QKV split epilogue
#pragma unroll
    for (int j = 0; j < 4; ++j) {
      const int col = n0 + 64 * wc + 16 * j + lq;
      if (col >= ncols) continue;
      const int seg = (col >= 1920) ? 2 : (col >= 960 ? 1 : 0);
      const int dcol = col - seg * 960;
      const float bv = bias[col];
#pragma unroll
      for (int i = 0; i < 6; ++i)
#pragma unroll
        for (int r = 0; r < 4; ++r) {
          const int row = m0 + 96 * wr + 16 * i + 4 * lh + r;  // b*1024+s
          if (row >= mMax) continue;
          const unsigned short v = f2bf(acc[i][j][r] + bv);
          if (seg == 0) outQ[(size_t)row * 960 + dcol] = v;
          else if (seg == 1) outK[(size_t)row * 960 + dcol] = v;
          else outV[((size_t)(row >> 10) << 20) + ((size_t)dcol << 10) + (row & 1023)] = v;
        }
    }
  }
}

// ---------------------------------------------------------------------------
// Fused scores + masked softmax (counted-vmcnt pipeline; unchanged from R5).
// ---------------------------------------------------------------------------
__global__ __launch_bounds__(512, 2) void attn_softmax(
    const unsigned short* __restrict__ Qb, const unsigned short* __restrict__ Kb,
    const int* __restrict__ mask, unsigned short* __restrict__ P) {
  __shared__ unsigned short Ks[2][1024 * 32];
  __shared__ unsigned short Qs[2][64 * 32];
  __shared__ float red[2][8][64];
  const int t = threadIdx.x, l = t & 63, w = t >> 6;
  const int flat = blockIdx.x;
  const int b = (flat & 7) * 4 + ((flat >> 3) >> 4);
  const int q0 = ((flat >> 3) & 15) * 64;
  const int lq = l & 15, lh = l >> 4;
  const size_t kbase = (size_t)b * 1024 * 960;
  const size_t qbase = ((size_t)b * 1024 + q0) * 960;
  const int lr = l >> 2, sg0 = l & 3;

#define STAGE(kkv, bufv)                                                      \
  {                                                                           \
    const int d0_ = (kkv) * 32;                                               \
    _Pragma("unroll") for (int i_ = 0; i_ < 8; ++i_) {                        \
      const int br_ = i_ * 128 + w * 16;                                      \
      const int kr_ = br_ + lr;                                               \
      const int sg_ = sg0 ^ ((kr_ >> 1) & 3);                                 \
      gload_lds16(Kb + kbase + (size_t)kr_ * 960 + d0_ + sg_ * 8,             \
                  (char*)Ks[(bufv)] + (size_t)br_ * 64);                      \
    }                                                                         \
    {                                                                         \
      const int qw_ = w & 3;                                                  \
      const int qr_ = qw_ * 16 + lr;                                          \
      const int sg_ = sg0 ^ ((qr_ >> 1) & 3);                                 \
      gload_lds16(Qb + qbase + (size_t)qr_ * 960 + d0_ + sg_ * 8,             \
                  (char*)Qs[(bufv)] + (size_t)(qw_ * 16) * 64);               \
    }                                                                         \
  }

  f32x4 acc[4][8] = {};
  STAGE(0, 0);
  int buf = 0;
  for (int kk = 0; kk < 30; ++kk) {
    if (kk < 29) {
      STAGE(kk + 1, buf ^ 1);
      asm volatile("s_waitcnt vmcnt(9)" ::: "memory");
    } else {
      asm volatile("s_waitcnt vmcnt(0)" ::: "memory");
    }
    __builtin_amdgcn_sched_barrier(0);
    __builtin_amdgcn_s_barrier();
    bf16x8 aF[4], bF[8];
#pragma unroll
    for (int i = 0; i < 4; ++i) {
      const int qr = 16 * i + lq;
      aF[i] = *(const bf16x8*)(Qs[buf] + qr * 32 + (lh ^ ((qr >> 1) & 3)) * 8);
    }
#pragma unroll
    for (int j = 0; j < 8; ++j) {
      const int kr = 128 * w + 16 * j + lq;
      bF[j] = *(const bf16x8*)(Ks[buf] + kr * 32 + (lh ^ ((kr >> 1) & 3)) * 8);
    }
#pragma unroll
    for (int i = 0; i < 4; ++i)
#pragma unroll
      for (int j = 0; j < 8; ++j) acc[i][j] = MFMA16(aF[i], bF[j], acc[i][j]);
    __builtin_amdgcn_s_barrier();
    buf ^= 1;
  }
#undef STAGE

#pragma unroll
  for (int j = 0; j < 8; ++j) {
    const int k = 128 * w + 16 * j + lq;
    if (mask[b * 1024 + k] == 0) {
#pragma unroll
      for (int i = 0; i < 4; ++i)
#pragma unroll
        for (int r = 0; r < 4; ++r) acc[i][j][r] = -1e9f;
    }
  }

  float rmax[4][4];
#pragma unroll
  for (int i = 0; i < 4; ++i)
#pragma unroll
    for (int r = 0; r < 4; ++r) {
      float m = acc[i][0][r];
#pragma unroll
      for (int j = 1; j < 8; ++j) m = fmaxf(m, acc[i][j][r]);
      m = fmaxf(m, __shfl_xor(m, 1));
      m = fmaxf(m, __shfl_xor(m, 2));
      m = fmaxf(m, __shfl_xor(m, 4));
      m = fmaxf(m, __shfl_xor(m, 8));
      rmax[i][r] = m;
    }
  if (lq == 0) {
#pragma unroll
    for (int i = 0; i < 4; ++i)
#pragma unroll
      for (int r = 0; r < 4; ++r) red[0][w][16 * i + 4 * lh + r] = rmax[i][r];
  }
  __syncthreads();
#pragma unroll
  for (int i = 0; i < 4; ++i)
#pragma unroll
    for (int r = 0; r < 4; ++r) {
      const int rowi = 16 * i + 4 * lh + r;
      float m = red[0][0][rowi];
#pragma unroll
      for (int w2 = 1; w2 < 8; ++w2) m = fmaxf(m, red[0][w2][rowi]);
      rmax[i][r] = m;
    }

  float rsum[4][4];
#pragma unroll
  for (int i = 0; i < 4; ++i)
#pragma unroll
    for (int r = 0; r < 4; ++r) {
      float s = 0.f;
#pragma unroll
      for (int j = 0; j < 8; ++j) {
        const float e = __expf(acc[i][j][r] - rmax[i][r]);
        acc[i][j][r] = e;
        s += e;
      }
      s += __shfl_xor(s, 1); s += __shfl_xor(s, 2);
      s += __shfl_xor(s, 4); s += __shfl_xor(s, 8);
      rsum[i][r] = s;
    }
  if (lq == 0) {
#pragma unroll
    for (int i = 0; i < 4; ++i)
#pragma unroll
      for (int r = 0; r < 4; ++r) red[1][w][16 * i + 4 * lh + r] = rsum[i][r];
  }
  __syncthreads();

  const size_t pb = ((size_t)b << 20) + (size_t)q0 * 1024;
#pragma unroll
  for (int i = 0; i < 4; ++i)
#pragma unroll
    for (int r = 0; r < 4; ++r) {
      const int rowi = 16 * i + 4 * lh + r;
      float s = 0.f;
#pragma unroll
      for (int w2 = 0; w2 < 8; ++w2) s += red[1][w2][rowi];
      const float inv = 1.0f / s;
#pragma unroll
      for (int j = 0; j < 8; ++j) {
        const int col = 128 * w + 16 * j + lq;
        P[pb + (size_t)rowi * 1024 + col] = f2bf(acc[i][j][r] * inv);
      }
    }
}

// ---------------------------------------------------------------------------
// h = bf16(ctx) + x; LayerNorm(h)*g+b; pooled[b,d] += y for masked rows.
// ---------------------------------------------------------------------------
__global__ __launch_bounds__(256) void ln_pool(
    const unsigned short* __restrict__ ctxb, const float* __restrict__ x,
    const int* __restrict__ mask, const float* __restrict__ g,
    const float* __restrict__ bta, float* __restrict__ pooled) {
  const int b = blockIdx.y, chunk = blockIdx.x;
  const int w = threadIdx.x >> 6, l = threadIdx.x & 63;
  f32x4 gc[4], bc[4];
#pragma unroll
  for (int c = 0; c < 4; ++c) {
    const int i4 = c * 64 + l;
    if (i4 < 240) {
      gc[c] = *(const f32x4*)(g + i4 * 4);
      bc[c] = *(const f32x4*)(bta + i4 * 4);
    }
  }
  f32x4 accp[4] = {};
  for (int rr = 0; rr < 8; ++rr) {
    const int s = chunk * 32 + w * 8 + rr;
    if (mask[b * 1024 + s] == 0) continue;
    const size_t base = ((size_t)b * 1024 + s) * 960;
    f32x4 h[4];
    float part = 0.f;
#pragma unroll
    for (int c = 0; c < 4; ++c) {
      const int i4 = c * 64 + l;
      if (i4 < 240) {
        u16x4 cv = *(const u16x4*)(ctxb + base + (size_t)i4 * 4);
        f32x4 xv = *(const f32x4*)(x + base + (size_t)i4 * 4);
        h[c][0] = bf2f(cv[0]) + xv[0];
        h[c][1] = bf2f(cv[1]) + xv[1];
        h[c][2] = bf2f(cv[2]) + xv[2];
        h[c][3] = bf2f(cv[3]) + xv[3];
        part += h[c][0] + h[c][1] + h[c][2] + h[c][3];
      } else {
        h[c] = 0;
      }
    }
#pragma unroll
    for (int o = 1; o < 64; o <<= 1) part += __shfl_xor(part, o);
    const float mu = part * (1.0f / 960.0f);
    float p2 = 0.f;
#pragma unroll
    for (int c = 0; c < 4; ++c) {
      if (c * 64 + l < 240) {
#pragma unroll
        for (int k2 = 0; k2 < 4; ++k2) {
          const float d = h[c][k2] - mu;
          p2 += d * d;
        }
      }
    }
#pragma unroll
    for (int o = 1; o < 64; o <<= 1) p2 += __shfl_xor(p2, o);
    const float rs = rsqrtf(p2 * (1.0f / 960.0f) + 1e-5f);
#pragma unroll
    for (int c = 0; c < 4; ++c) {
      if (c * 64 + l < 240) {
#pragma unroll
        for (int k2 = 0; k2 < 4; ++k2)
          accp[c][k2] += (h[c][k2] - mu) * rs * gc[c][k2] + bc[c][k2];
      }
    }
  }
#pragma unroll
  for (int c = 0; c < 4; ++c) {
    const int i4 = c * 64 + l;
    if (i4 < 240) {
#pragma unroll
      for (int k2 = 0; k2 < 4; ++k2) atomicAdd(&pooled[b * 960 + i4 * 4 + k2], accp[c][k2]);
    }
  }
}

// ---------------------------------------------------------------------------
// pooled/count -> 960-512-256-128-10 MLP fp32. One block per batch row.
// ---------------------------------------------------------------------------
__global__ __launch_bounds__(256) void mlp_head(
    const float* __restrict__ pooled, const int* __restrict__ mask,
    const float* __restrict__ W1, const float* __restrict__ b1,
    const float* __restrict__ W2, const float* __restrict__ b2,
    const float* __restrict__ W3, const float* __restrict__ b3,
    const float* __restrict__ W4, const float* __restrict__ b4, float* __restrict__ out) {
  __shared__ float h0[960], h1[512], h2[256], h3[128];
  __shared__ float csh[4];
  const int b = blockIdx.x, t = threadIdx.x;
  int cnt = 0;
  for (int s = t; s < 1024; s += 256) cnt += (mask[b * 1024 + s] != 0) ? 1 : 0;
#pragma unroll
  for (int o = 1; o < 64; o <<= 1) cnt += __shfl_xor(cnt, o);
  if ((t & 63) == 0) csh[t >> 6] = (float)cnt;
  __syncthreads();
  const float inv = 1.0f / fmaxf(csh[0] + csh[1] + csh[2] + csh[3], 1e-9f);
  for (int d = t; d < 960; d += 256) h0[d] = pooled[b * 960 + d] * inv;
  __syncthreads();
  for (int o = t; o < 512; o += 256) {
    float a = b1[o];
    const float* wr = W1 + (size_t)o * 960;
    for (int k = 0; k < 960; k += 4) {
      f32x4 wv = *(const f32x4*)(wr + k);
      f32x4 hv = *(const f32x4*)(h0 + k);
      a += wv[0] * hv[0] + wv[1] * hv[1] + wv[2] * hv[2] + wv[3] * hv[3];
    }
    h1[o] = fmaxf(a, 0.f);
  }
  __syncthreads();
  {
    float a = b2[t];
    const float* wr = W2 + (size_t)t * 512;
    for (int k = 0; k < 512; k += 4) {
      f32x4 wv = *(const f32x4*)(wr + k);
      f32x4 hv = *(const f32x4*)(h1 + k);
      a += wv[0] * hv[0] + wv[1] * hv[1] + wv[2] * hv[2] + wv[3] * hv[3];
    }
    h2[t] = fmaxf(a, 0.f);
  }
  __syncthreads();
  if (t < 128) {
    float a = b3[t];
    const float* wr = W3 + (size_t)t * 256;
    for (int k = 0; k < 256; k += 4) {
      f32x4 wv = *(const f32x4*)(wr + k);
      f32x4 hv = *(const f32x4*)(h2 + k);
      a += wv[0] * hv[0] + wv[1] * hv[1] + wv[2] * hv[2] + wv[3] * hv[3];
    }
    h3[t] = fmaxf(a, 0.f);
  }
  __syncthreads();
  if (t < 10) {
    float a = b4[t];
    const float* wr = W4 + (size_t)t * 128;
    for (int k = 0; k < 128; ++k) a += wr[k] * h3[k];
    out[b * 10 + t] = a;
  }
}

// ---------------------------------------------------------------------------
// Workspace (bytes):
//   [0,          67108864)  xb bf16 [32768][1024] -> P bf16 [32][1024][1024]
//   [67108864,  130023424)  Qb bf16 [32768][960]  -> ctx bf16 [32768][960]
//   [130023424, 192937984)  Kb bf16 [32768][960]
//   [192937984, 260046848)  Vt bf16 [32][1024][1024] (d rows 960+ garbage)
//   [260046848, 266338304)  Wqkv bf16 [3072][1024]
//   [266338304, 266349824)  biasQKV f32 [2880]
//   [266349824, 266472704)  pooled f32 [32][960]
// ---------------------------------------------------------------------------
extern "C" void kernel_launch(void* const* d_in, const int* in_sizes, int n_in,
                              void* d_out, int out_size, void* d_ws, size_t ws_size,
                              hipStream_t stream) {
  (void)in_sizes; (void)n_in; (void)out_size; (void)ws_size;
  const float* x    = (const float*)d_in[0];
  const int*   mask = (const int*)d_in[1];
  const float* Wq   = (const float*)d_in[2];
  const float* bq   = (const float*)d_in[3];
  const float* Wk   = (const float*)d_in[4];
  const float* bk   = (const float*)d_in[5];
  const float* Wv   = (const float*)d_in[6];
  const float* bv   = (const float*)d_in[7];
  const float* lng  = (const float*)d_in[8];
  const float* lnb  = (const float*)d_in[9];
  const float* W1   = (const float*)d_in[10];
  const float* b1   = (const float*)d_in[11];
  const float* W2   = (const float*)d_in[12];
  const float* b2   = (const float*)d_in[13];
  const float* W3   = (const float*)d_in[14];
  const float* b3   = (const float*)d_in[15];
  const float* W4   = (const float*)d_in[16];
  const float* b4   = (const float*)d_in[17];
  float* out = (float*)d_out;

  char* ws = (char*)d_ws;
  unsigned short* xb     = (unsigned short*)(ws);
  unsigned short* P      = (unsigned short*)(ws);            // over dead xb
  unsigned short* Qb     = (unsigned short*)(ws + 67108864);
  unsigned short* Kb     = (unsigned short*)(ws + 130023424);
  unsigned short* ctxb   = (unsigned short*)(ws + 67108864); // over dead Qb
  unsigned short* Vt     = (unsigned short*)(ws + 192937984);
  unsigned short* Wqkv   = (unsigned short*)(ws + 260046848);
  float*          biasQ  = (float*)(ws + 266338304);
  float*          pooled = (float*)(ws + 266349824);

  const float scaleQ = 0.0322748612183951f;  // 1/sqrt(960)

  cast_wqkv<<<2880, 256, 0, stream>>>(Wq, Wk, Wv, bq, bk, bv, Wqkv, biasQ, scaleQ);
  cast_x<<<8192, 256, 0, stream>>>(x, xb);

  // fused QKV: [32768 x 2880] = xb[32768x1024] . Wqkv^T; writes Qb, Kb, Vt(T)
  // mTiles=171 (ceil 32768/192), nTiles=23 (ceil 2880/128), nkt=16 (K=1024 pad)
  gemmY<1><<<171 * 23, 256, 0, stream>>>(
      xb, Wqkv, 1024, 1024, biasQ, nullptr, Qb, Kb, Vt,
      171, 23, 16, 32768, 2880, 0, 0, 0, 0);

  attn_softmax<<<512, 512, 0, stream>>>(Qb, Kb, mask, P);

  // ctx[b] = P[b] . Vt[b]^T : M=1024 (6 tiles), N=960 (8 tiles), K=1024,
  // bf16 out over dead Qb
  gemmY<2><<<6 * 8 * 32, 256, 0, stream>>>(
      P, Vt, 1024, 1024, nullptr, ctxb, nullptr, nullptr, nullptr,
      6, 8, 16, 1024, 960, 960, (size_t)1048576, (size_t)1048576, (size_t)983040);

  hipMemsetAsync(pooled, 0, 32 * 960 * 4, stream);
  ln_pool<<<dim3(32, 32), 256, 0, stream>>>(ctxb, x, mask, lng, lnb, pooled);
  mlp_head<<<32, 256, 0, stream>>>(pooled, mask, W1, b1, W2, b2, W3, b3, W4, b4, out);
}

// Round 7
// 719.614 us; speedup vs baseline: 1.0602x; 1.0602x over previous
//
#include <hip/hip_runtime.h>

// ---------------------------------------------------------------------------
// DeepProteinClassifier: x[32,1024,960] fp32, mask[32,1024] i32 ->
//   fused QKV proj -> fused attention (scores+softmax) -> PV GEMM (bf16 ctx)
//   -> +x, LN -> masked mean pool -> MLP -> [32,10] f32
// gemm3r: BM=256/BN=128/BK=64, 8 waves (4Mx2N, 64x64/wave), 3-slot LDS ring
// (144KB), 2 phases/K-tile, counted vmcnt(6) once per K-tile (never drains),
// ds_reads issued pre-barrier, lgkmcnt(0)+sched_barrier before MFMA (rule 18).
// ---------------------------------------------------------------------------

#define DEVINL __device__ __forceinline__

typedef __attribute__((ext_vector_type(8))) short bf16x8;
typedef __attribute__((ext_vector_type(4))) float f32x4;
typedef __attribute__((ext_vector_type(4))) unsigned short u16x4;

DEVINL unsigned short f2bf(float f) {
  unsigned int u = __float_as_uint(f);
  u += 0x7FFFu + ((u >> 16) & 1u);  // round-to-nearest-even
  return (unsigned short)(u >> 16);
}

DEVINL float bf2f(unsigned short h) { return __uint_as_float(((unsigned int)h) << 16); }

DEVINL void gload_lds16(const void* g, void* l) {
  __builtin_amdgcn_global_load_lds((const __attribute__((address_space(1))) unsigned int*)g,
                                   (__attribute__((address_space(3))) unsigned int*)l,
                                   16, 0, 0);
}

#define MFMA16(a, b, c) __builtin_amdgcn_mfma_f32_16x16x32_bf16((a), (b), (c), 0, 0, 0)

// ---------------------------------------------------------------------------
// Build Wqkv [3072][1024] bf16 (rows 0..959 Wq*scale, 960..1919 Wk,
// 1920..2879 Wv; cols 960..1023 zero) and biasQKV[2880] f32.
// ---------------------------------------------------------------------------
__global__ __launch_bounds__(256) void cast_wqkv(
    const float* __restrict__ Wq, const float* __restrict__ Wk, const float* __restrict__ Wv,
    const float* __restrict__ bq, const float* __restrict__ bk, const float* __restrict__ bv,
    unsigned short* __restrict__ Wqkv, float* __restrict__ biasQ, float scaleQ) {
  const int r = blockIdx.x, t = threadIdx.x;
  const int seg = (r >= 1920) ? 2 : (r >= 960 ? 1 : 0);
  const int sr = r - seg * 960;
  const float* W = (seg == 0) ? Wq : (seg == 1) ? Wk : Wv;
  const float sc = (seg == 0) ? scaleQ : 1.0f;
  if (t < 240) {
    f32x4 v = *(const f32x4*)(W + (size_t)sr * 960 + t * 4);
    u16x4 o;
    o[0] = f2bf(v[0] * sc); o[1] = f2bf(v[1] * sc);
    o[2] = f2bf(v[2] * sc); o[3] = f2bf(v[3] * sc);
    *(u16x4*)(Wqkv + (size_t)r * 1024 + t * 4) = o;
  } else {
    u16x4 z = {};
    *(u16x4*)(Wqkv + (size_t)r * 1024 + 960 + (t - 240) * 4) = z;
  }
  if (t == 0) {
    const float* bb = (seg == 0) ? bq : (seg == 1) ? bk : bv;
    biasQ[r] = bb[sr] * sc;
  }
}

// ---------------------------------------------------------------------------
// cast x [32768][960] f32 -> xb [32768][1024] bf16 (cols 960.. zero).
// ---------------------------------------------------------------------------
__global__ __launch_bounds__(256) void cast_x(
    const float* __restrict__ x, unsigned short* __restrict__ xb) {
  const int row = blockIdx.x * 4 + (threadIdx.x >> 6);
  const int l = threadIdx.x & 63;
  unsigned short* o = xb + (size_t)row * 1024 + l * 16;
  if (l < 60) {
    const float* g = x + (size_t)row * 960 + l * 16;
    f32x4 v0 = *(const f32x4*)(g);
    f32x4 v1 = *(const f32x4*)(g + 4);
    f32x4 v2 = *(const f32x4*)(g + 8);
    f32x4 v3 = *(const f32x4*)(g + 12);
    bf16x8 o0, o1;
    o0[0] = (short)f2bf(v0[0]); o0[1] = (short)f2bf(v0[1]);
    o0[2] = (short)f2bf(v0[2]); o0[3] = (short)f2bf(v0[3]);
    o0[4] = (short)f2bf(v1[0]); o0[5] = (short)f2bf(v1[1]);
    o0[6] = (short)f2bf(v1[2]); o0[7] = (short)f2bf(v1[3]);
    o1[0] = (short)f2bf(v2[0]); o1[1] = (short)f2bf(v2[1]);
    o1[2] = (short)f2bf(v2[2]); o1[3] = (short)f2bf(v2[3]);
    o1[4] = (short)f2bf(v3[0]); o1[5] = (short)f2bf(v3[1]);
    o1[6] = (short)f2bf(v3[2]); o1[7] = (short)f2bf(v3[3]);
    *(bf16x8*)(o) = o0;
    *(bf16x8*)(o + 8) = o1;
  } else {
    bf16x8 z = {};
    *(bf16x8*)(o) = z;
    *(bf16x8*)(o + 8) = z;
  }
}

// ---------------------------------------------------------------------------
// gemm3r: 256x128 NT GEMM, BK=64, K=1024 (16 K-tiles) fixed.
// 8 waves: wr=w>>1 (4 M-quads), wc=w&1 (2 N-halves); per-wave 64x64, acc[4][4].
// LDS ring: As[3][256*64] + Bs[3][128*64] = 144 KB; stage kt+2 while
// computing kt; 6 gloads/thread/K-tile (A:4 rounds of 64 rows, B:2).
// Phase/K-tile = kk half: {8 ds_read; 3 gload; [phase1: vmcnt(6)]; barrier;
// lgkmcnt(0)+sched_barrier; setprio(1) 16 MFMA setprio(0); barrier}.
// MODE 1: QKV epilogue (bf16 +bias -> Qb/Kb/Vt-transposed).
// MODE 2: bf16 out (PV -> ctx bf16).
// Bijective XCD-chunked swizzle; n-tile fastest (A-panel L2 reuse).
// ---------------------------------------------------------------------------
template <int MODE>
__global__ __launch_bounds__(512, 2) void gemm3r(
    const unsigned short* __restrict__ Ap, const unsigned short* __restrict__ Bp,
    int lda, int ldb, const float* __restrict__ bias,
    unsigned short* __restrict__ outC, unsigned short* __restrict__ outQ,
    unsigned short* __restrict__ outK, unsigned short* __restrict__ outV,
    int mTiles, int nTiles, int ncols, int ldo,
    size_t aStride, size_t bStride, size_t oStride) {
  __shared__ unsigned short As[3][256 * 64];
  __shared__ unsigned short Bs[3][128 * 64];
  const int t = threadIdx.x, l = t & 63, w = t >> 6;
  const int wr = w >> 1, wc = w & 1;
  const int lq = l & 15, lh = l >> 4;

  // bijective XCD-chunked swizzle (m204)
  const int nwg = (int)gridDim.x;
  const int flat = (int)blockIdx.x;
  const int q8 = nwg >> 3, r8 = nwg & 7, xcd = flat & 7;
  const int wgid = (xcd < r8 ? xcd * (q8 + 1) : r8 * (q8 + 1) + (xcd - r8) * q8) + (flat >> 3);
  const int pt = mTiles * nTiles;
  const int zb = wgid / pt;
  const int rm = wgid - zb * pt;
  const int mi = rm / nTiles;
  const int m0 = mi * 256;
  const int n0 = (rm - mi * nTiles) * 128;

  const unsigned short* A = Ap + (size_t)zb * aStride + (size_t)m0 * lda;
  const unsigned short* B = Bp + (size_t)zb * bStride + (size_t)n0 * ldb;

  // --- staging: round p covers rows [64p,64p+64); per-wave 8 rows, lane->slot
#define STAGE_A3(KT, SL)                                                      \
  _Pragma("unroll") for (int p_ = 0; p_ < 3; ++p_) {                          \
    const int r_ = p_ * 64 + w * 8 + (l >> 3);                                \
    const int sg_ = (l & 7) ^ (r_ & 7);                                       \
    gload_lds16(A + (size_t)r_ * lda + (KT) * 64 + sg_ * 8,                   \
                (char*)&As[SL][(size_t)(p_ * 64 + w * 8) * 64]);              \
  }
#define STAGE_A1B2(KT, SL)                                                    \
  {                                                                           \
    const int r_ = 192 + w * 8 + (l >> 3);                                    \
    const int sg_ = (l & 7) ^ (r_ & 7);                                       \
    gload_lds16(A + (size_t)r_ * lda + (KT) * 64 + sg_ * 8,                   \
                (char*)&As[SL][(size_t)(192 + w * 8) * 64]);                  \
  }                                                                           \
  _Pragma("unroll") for (int p_ = 0; p_ < 2; ++p_) {                          \
    const int r_ = p_ * 64 + w * 8 + (l >> 3);                                \
    const int sg_ = (l & 7) ^ (r_ & 7);                                       \
    gload_lds16(B + (size_t)r_ * ldb + (KT) * 64 + sg_ * 8,                   \
                (char*)&Bs[SL][(size_t)(p_ * 64 + w * 8) * 64]);              \
  }

#define READQ(KK)                                                             \
  _Pragma("unroll") for (int i_ = 0; i_ < 4; ++i_) {                          \
    const int r_ = wr * 64 + 16 * i_ + lq;                                    \
    aF[i_] = *(const bf16x8*)&As[s][(size_t)r_ * 64 +                         \
                                    ((((KK) << 2) | lh) ^ (r_ & 7)) * 8];     \
  }                                                                           \
  _Pragma("unroll") for (int j_ = 0; j_ < 4; ++j_) {                          \
    const int r_ = wc * 64 + 16 * j_ + lq;                                    \
    bF[j_] = *(const bf16x8*)&Bs[s][(size_t)r_ * 64 +                         \
                                    ((((KK) << 2) | lh) ^ (r_ & 7)) * 8];     \
  }

#define DOMFMA                                                                \
  _Pragma("unroll") for (int i_ = 0; i_ < 4; ++i_)                            \
    _Pragma("unroll") for (int j_ = 0; j_ < 4; ++j_)                          \
      acc[i_][j_] = MFMA16(aF[i_], bF[j_], acc[i_][j_]);

  f32x4 acc[4][4] = {};

  // prologue: stage kt0 -> slot0, kt1 -> slot1 (12 loads); oldest 6 = kt0
  STAGE_A3(0, 0); STAGE_A1B2(0, 0);
  STAGE_A3(1, 1); STAGE_A1B2(1, 1);
  asm volatile("s_waitcnt vmcnt(6)" ::: "memory");  // kt0 landed; kt1 in flight
  __builtin_amdgcn_s_barrier();

  int s = 0;
  for (int kt = 0; kt < 16; ++kt) {
    const int s2 = (s >= 1) ? s - 1 : 2;  // (s+2)%3
    {  // ---- phase 0 (kk=0): reads slot s; stages 3/6 of kt+2
      bf16x8 aF[4], bF[4];
      READQ(0);
      if (kt < 14) { STAGE_A3(kt + 2, s2); }
      __builtin_amdgcn_s_barrier();
      asm volatile("s_waitcnt lgkmcnt(0)" ::: "memory");
      __builtin_amdgcn_sched_barrier(0);
      __builtin_amdgcn_s_setprio(1);
      DOMFMA;
      __builtin_amdgcn_s_setprio(0);
      __builtin_amdgcn_s_barrier();
    }
    {  // ---- phase 1 (kk=1): reads slot s; stages 3/6 of kt+2; counted wait
      bf16x8 aF[4], bF[4];
      READQ(1);
      if (kt < 14) {
        STAGE_A1B2(kt + 2, s2);
        __builtin_amdgcn_sched_barrier(0);
        asm volatile("s_waitcnt vmcnt(6)" ::: "memory");  // kt+1 landed; kt+2 in flight
      } else if (kt == 14) {
        asm volatile("s_waitcnt vmcnt(0)" ::: "memory");  // final drain: kt15 landed
      }
      __builtin_amdgcn_s_barrier();
      asm volatile("s_waitcnt lgkmcnt(0)" ::: "memory");
      __builtin_amdgcn_sched_barrier(0);
      __builtin_amdgcn_s_setprio(1);
      DOMFMA;
      __builtin_amdgcn_s_setprio(0);
      __builtin_amdgcn_s_barrier();
    }
    s = (s == 2) ? 0 : s + 1;
  }
#undef STAGE_A3
#undef STAGE_A1B2
#undef READQ
#undef DOMFMA

  // epilogue: C/D layout col = lane&15, row = (lane>>4)*4 + reg
  if (MODE == 2) {  // bf16 ctx out
#pragma unroll
    for (int j = 0; j < 4; ++j) {
      const int col = n0 + 64 * wc + 16 * j + lq;
      if (col >= ncols) continue;
#pragma unroll
      for (int i = 0; i < 4; ++i)
#pragma unroll
        for (int r = 0; r < 4; ++r) {
          const int row = m0 + 64 * wr + 16 * i + 4 * lh + r;
          outC[(size_t)zb * oStride + (size_t)row * ldo + col] = f2bf(acc[i][j][r]);
        }
    }
  } else {  // MODE 1: QKV split epilogue
#pragma unroll
    for (int j = 0; j < 4; ++j) {
      const int col = n0 + 64 * wc + 16 * j + lq;
      if (col >= ncols) continue;
      const int seg = (col >= 1920) ? 2 : (col >= 960 ? 1 : 0);
      const int dcol = col - seg * 960;
      const float bv = bias[col];
#pragma unroll
      for (int i = 0; i < 4; ++i)
#pragma unroll
        for (int r = 0; r < 4; ++r) {
          const int row = m0 + 64 * wr + 16 * i + 4 * lh + r;  // b*1024+s
          const unsigned short v = f2bf(acc[i][j][r] + bv);
          if (seg == 0) outQ[(size_t)row * 960 + dcol] = v;
          else if (seg == 1) outK[(size_t)row * 960 + dcol] = v;
          else outV[((size_t)(row >> 10) << 20) + ((size_t)dcol << 10) + (row & 1023)] = v;
        }
    }
  }
}

// ---------------------------------------------------------------------------
// Fused scores + masked softmax (counted-vmcnt pipeline; unchanged from R5).
// ---------------------------------------------------------------------------
__global__ __launch_bounds__(512, 2) void attn_softmax(
    const unsigned short* __restrict__ Qb, const unsigned short* __restrict__ Kb,
    const int* __restrict__ mask, unsigned short* __restrict__ P) {
  __shared__ unsigned short Ks[2][1024 * 32];
  __shared__ unsigned short Qs[2][64 * 32];
  __shared__ float red[2][8][64];
  const int t = threadIdx.x, l = t & 63, w = t >> 6;
  const int flat = blockIdx.x;
  const int b = (flat & 7) * 4 + ((flat >> 3) >> 4);
  const int q0 = ((flat >> 3) & 15) * 64;
  const int lq = l & 15, lh = l >> 4;
  const size_t kbase = (size_t)b * 1024 * 960;
  const size_t qbase = ((size_t)b * 1024 + q0) * 960;
  const int lr = l >> 2, sg0 = l & 3;

#define STAGE(kkv, bufv)                                                      \
  {                                                                           \
    const int d0_ = (kkv) * 32;                                               \
    _Pragma("unroll") for (int i_ = 0; i_ < 8; ++i_) {                        \
      const int br_ = i_ * 128 + w * 16;                                      \
      const int kr_ = br_ + lr;                                               \
      const int sg_ = sg0 ^ ((kr_ >> 1) & 3);                                 \
      gload_lds16(Kb + kbase + (size_t)kr_ * 960 + d0_ + sg_ * 8,             \
                  (char*)Ks[(bufv)] + (size_t)br_ * 64);                      \
    }                                                                         \
    {                                                                         \
      const int qw_ = w & 3;                                                  \
      const int qr_ = qw_ * 16 + lr;                                          \
      const int sg_ = sg0 ^ ((qr_ >> 1) & 3);                                 \
      gload_lds16(Qb + qbase + (size_t)qr_ * 960 + d0_ + sg_ * 8,             \
                  (char*)Qs[(bufv)] + (size_t)(qw_ * 16) * 64);               \
    }                                                                         \
  }

  f32x4 acc[4][8] = {};
  STAGE(0, 0);
  int buf = 0;
  for (int kk = 0; kk < 30; ++kk) {
    if (kk < 29) {
      STAGE(kk + 1, buf ^ 1);
      asm volatile("s_waitcnt vmcnt(9)" ::: "memory");
    } else {
      asm volatile("s_waitcnt vmcnt(0)" ::: "memory");
    }
    __builtin_amdgcn_sched_barrier(0);
    __builtin_amdgcn_s_barrier();
    bf16x8 aF[4], bF[8];
#pragma unroll
    for (int i = 0; i < 4; ++i) {
      const int qr = 16 * i + lq;
      aF[i] = *(const bf16x8*)(Qs[buf] + qr * 32 + (lh ^ ((qr >> 1) & 3)) * 8);
    }
#pragma unroll
    for (int j = 0; j < 8; ++j) {
      const int kr = 128 * w + 16 * j + lq;
      bF[j] = *(const bf16x8*)(Ks[buf] + kr * 32 + (lh ^ ((kr >> 1) & 3)) * 8);
    }
#pragma unroll
    for (int i = 0; i < 4; ++i)
#pragma unroll
      for (int j = 0; j < 8; ++j) acc[i][j] = MFMA16(aF[i], bF[j], acc[i][j]);
    __builtin_amdgcn_s_barrier();
    buf ^= 1;
  }
#undef STAGE

#pragma unroll
  for (int j = 0; j < 8; ++j) {
    const int k = 128 * w + 16 * j + lq;
    if (mask[b * 1024 + k] == 0) {
#pragma unroll
      for (int i = 0; i < 4; ++i)
#pragma unroll
        for (int r = 0; r < 4; ++r) acc[i][j][r] = -1e9f;
    }
  }

  float rmax[4][4];
#pragma unroll
  for (int i = 0; i < 4; ++i)
#pragma unroll
    for (int r = 0; r < 4; ++r) {
      float m = acc[i][0][r];
#pragma unroll
      for (int j = 1; j < 8; ++j) m = fmaxf(m, acc[i][j][r]);
      m = fmaxf(m, __shfl_xor(m, 1));
      m = fmaxf(m, __shfl_xor(m, 2));
      m = fmaxf(m, __shfl_xor(m, 4));
      m = fmaxf(m, __shfl_xor(m, 8));
      rmax[i][r] = m;
    }
  if (lq == 0) {
#pragma unroll
    for (int i = 0; i < 4; ++i)
#pragma unroll
      for (int r = 0; r < 4; ++r) red[0][w][16 * i + 4 * lh + r] = rmax[i][r];
  }
  __syncthreads();
#pragma unroll
  for (int i = 0; i < 4; ++i)
#pragma unroll
    for (int r = 0; r < 4; ++r) {
      const int rowi = 16 * i + 4 * lh + r;
      float m = red[0][0][rowi];
#pragma unroll
      for (int w2 = 1; w2 < 8; ++w2) m = fmaxf(m, red[0][w2][rowi]);
      rmax[i][r] = m;
    }

  float rsum[4][4];
#pragma unroll
  for (int i = 0; i < 4; ++i)
#pragma unroll
    for (int r = 0; r < 4; ++r) {
      float s = 0.f;
#pragma unroll
      for (int j = 0; j < 8; ++j) {
        const float e = __expf(acc[i][j][r] - rmax[i][r]);
        acc[i][j][r] = e;
        s += e;
      }
      s += __shfl_xor(s, 1); s += __shfl_xor(s, 2);
      s += __shfl_xor(s, 4); s += __shfl_xor(s, 8);
      rsum[i][r] = s;
    }
  if (lq == 0) {
#pragma unroll
    for (int i = 0; i < 4; ++i)
#pragma unroll
      for (int r = 0; r < 4; ++r) red[1][w][16 * i + 4 * lh + r] = rsum[i][r];
  }
  __syncthreads();

  const size_t pb = ((size_t)b << 20) + (size_t)q0 * 1024;
#pragma unroll
  for (int i = 0; i < 4; ++i)
#pragma unroll
    for (int r = 0; r < 4; ++r) {
      const int rowi = 16 * i + 4 * lh + r;
      float s = 0.f;
#pragma unroll
      for (int w2 = 0; w2 < 8; ++w2) s += red[1][w2][rowi];
      const float inv = 1.0f / s;
#pragma unroll
      for (int j = 0; j < 8; ++j) {
        const int col = 128 * w + 16 * j + lq;
        P[pb + (size_t)rowi * 1024 + col] = f2bf(acc[i][j][r] * inv);
      }
    }
}

// ---------------------------------------------------------------------------
// h = bf16(ctx) + x; LayerNorm(h)*g+b; pooled[b,d] += y for masked rows.
// ---------------------------------------------------------------------------
__global__ __launch_bounds__(256) void ln_pool(
    const unsigned short* __restrict__ ctxb, const float* __restrict__ x,
    const int* __restrict__ mask, const float* __restrict__ g,
    const float* __restrict__ bta, float* __restrict__ pooled) {
  const int b = blockIdx.y, chunk = blockIdx.x;
  const int w = threadIdx.x >> 6, l = threadIdx.x & 63;
  f32x4 gc[4], bc[4];
#pragma unroll
  for (int c = 0; c < 4; ++c) {
    const int i4 = c * 64 + l;
    if (i4 < 240) {
      gc[c] = *(const f32x4*)(g + i4 * 4);
      bc[c] = *(const f32x4*)(bta + i4 * 4);
    }
  }
  f32x4 accp[4] = {};
  for (int rr = 0; rr < 8; ++rr) {
    const int s = chunk * 32 + w * 8 + rr;
    if (mask[b * 1024 + s] == 0) continue;
    const size_t base = ((size_t)b * 1024 + s) * 960;
    f32x4 h[4];
    float part = 0.f;
#pragma unroll
    for (int c = 0; c < 4; ++c) {
      const int i4 = c * 64 + l;
      if (i4 < 240) {
        u16x4 cv = *(const u16x4*)(ctxb + base + (size_t)i4 * 4);
        f32x4 xv = *(const f32x4*)(x + base + (size_t)i4 * 4);
        h[c][0] = bf2f(cv[0]) + xv[0];
        h[c][1] = bf2f(cv[1]) + xv[1];
        h[c][2] = bf2f(cv[2]) + xv[2];
        h[c][3] = bf2f(cv[3]) + xv[3];
        part += h[c][0] + h[c][1] + h[c][2] + h[c][3];
      } else {
        h[c] = 0;
      }
    }
#pragma unroll
    for (int o = 1; o < 64; o <<= 1) part += __shfl_xor(part, o);
    const float mu = part * (1.0f / 960.0f);
    float p2 = 0.f;
#pragma unroll
    for (int c = 0; c < 4; ++c) {
      if (c * 64 + l < 240) {
#pragma unroll
        for (int k2 = 0; k2 < 4; ++k2) {
          const float d = h[c][k2] - mu;
          p2 += d * d;
        }
      }
    }
#pragma unroll
    for (int o = 1; o < 64; o <<= 1) p2 += __shfl_xor(p2, o);
    const float rs = rsqrtf(p2 * (1.0f / 960.0f) + 1e-5f);
#pragma unroll
    for (int c = 0; c < 4; ++c) {
      if (c * 64 + l < 240) {
#pragma unroll
        for (int k2 = 0; k2 < 4; ++k2)
          accp[c][k2] += (h[c][k2] - mu) * rs * gc[c][k2] + bc[c][k2];
      }
    }
  }
#pragma unroll
  for (int c = 0; c < 4; ++c) {
    const int i4 = c * 64 + l;
    if (i4 < 240) {
#pragma unroll
      for (int k2 = 0; k2 < 4; ++k2) atomicAdd(&pooled[b * 960 + i4 * 4 + k2], accp[c][k2]);
    }
  }
}

// ---------------------------------------------------------------------------
// pooled/count -> 960-512-256-128-10 MLP fp32. One block per batch row.
// ---------------------------------------------------------------------------
__global__ __launch_bounds__(256) void mlp_head(
    const float* __restrict__ pooled, const int* __restrict__ mask,
    const float* __restrict__ W1, const float* __restrict__ b1,
    const float* __restrict__ W2, const float* __restrict__ b2,
    const float* __restrict__ W3, const float* __restrict__ b3,
    const float* __restrict__ W4, const float* __restrict__ b4, float* __restrict__ out) {
  __shared__ float h0[960], h1[512], h2[256], h3[128];
  __shared__ float csh[4];
  const int b = blockIdx.x, t = threadIdx.x;
  int cnt = 0;
  for (int s = t; s < 1024; s += 256) cnt += (mask[b * 1024 + s] != 0) ? 1 : 0;
#pragma unroll
  for (int o = 1; o < 64; o <<= 1) cnt += __shfl_xor(cnt, o);
  if ((t & 63) == 0) csh[t >> 6] = (float)cnt;
  __syncthreads();
  const float inv = 1.0f / fmaxf(csh[0] + csh[1] + csh[2] + csh[3], 1e-9f);
  for (int d = t; d < 960; d += 256) h0[d] = pooled[b * 960 + d] * inv;
  __syncthreads();
  for (int o = t; o < 512; o += 256) {
    float a = b1[o];
    const float* wr = W1 + (size_t)o * 960;
    for (int k = 0; k < 960; k += 4) {
      f32x4 wv = *(const f32x4*)(wr + k);
      f32x4 hv = *(const f32x4*)(h0 + k);
      a += wv[0] * hv[0] + wv[1] * hv[1] + wv[2] * hv[2] + wv[3] * hv[3];
    }
    h1[o] = fmaxf(a, 0.f);
  }
  __syncthreads();
  {
    float a = b2[t];
    const float* wr = W2 + (size_t)t * 512;
    for (int k = 0; k < 512; k += 4) {
      f32x4 wv = *(const f32x4*)(wr + k);
      f32x4 hv = *(const f32x4*)(h1 + k);
      a += wv[0] * hv[0] + wv[1] * hv[1] + wv[2] * hv[2] + wv[3] * hv[3];
    }
    h2[t] = fmaxf(a, 0.f);
  }
  __syncthreads();
  if (t < 128) {
    float a = b3[t];
    const float* wr = W3 + (size_t)t * 256;
    for (int k = 0; k < 256; k += 4) {
      f32x4 wv = *(const f32x4*)(wr + k);
      f32x4 hv = *(const f32x4*)(h2 + k);
      a += wv[0] * hv[0] + wv[1] * hv[1] + wv[2] * hv[2] + wv[3] * hv[3];
    }
    h3[t] = fmaxf(a, 0.f);
  }
  __syncthreads();
  if (t < 10) {
    float a = b4[t];
    const float* wr = W4 + (size_t)t * 128;
    for (int k = 0; k < 128; ++k) a += wr[k] * h3[k];
    out[b * 10 + t] = a;
  }
}

// ---------------------------------------------------------------------------
// Workspace (bytes):
//   [0,          67108864)  xb bf16 [32768][1024] -> P bf16 [32][1024][1024]
//   [67108864,  130023424)  Qb bf16 [32768][960]  -> ctx bf16 [32768][960]
//   [130023424, 192937984)  Kb bf16 [32768][960]
//   [192937984, 260046848)  Vt bf16 [32][1024][1024] (d rows 960+ garbage)
//   [260046848, 266338304)  Wqkv bf16 [3072][1024] (rows 2880+ garbage-read)
//   [266338304, 266349824)  biasQKV f32 [2880]
//   [266349824, 266472704)  pooled f32 [32][960]
// ---------------------------------------------------------------------------
extern "C" void kernel_launch(void* const* d_in, const int* in_sizes, int n_in,
                              void* d_out, int out_size, void* d_ws, size_t ws_size,
                              hipStream_t stream) {
  (void)in_sizes; (void)n_in; (void)out_size; (void)ws_size;
  const float* x    = (const float*)d_in[0];
  const int*   mask = (const int*)d_in[1];
  const float* Wq   = (const float*)d_in[2];
  const float* bq   = (const float*)d_in[3];
  const float* Wk   = (const float*)d_in[4];
  const float* bk   = (const float*)d_in[5];
  const float* Wv   = (const float*)d_in[6];
  const float* bv   = (const float*)d_in[7];
  const float* lng  = (const float*)d_in[8];
  const float* lnb  = (const float*)d_in[9];
  const float* W1   = (const float*)d_in[10];
  const float* b1   = (const float*)d_in[11];
  const float* W2   = (const float*)d_in[12];
  const float* b2   = (const float*)d_in[13];
  const float* W3   = (const float*)d_in[14];
  const float* b3   = (const float*)d_in[15];
  const float* W4   = (const float*)d_in[16];
  const float* b4   = (const float*)d_in[17];
  float* out = (float*)d_out;

  char* ws = (char*)d_ws;
  unsigned short* xb     = (unsigned short*)(ws);
  unsigned short* P      = (unsigned short*)(ws);            // over dead xb
  unsigned short* Qb     = (unsigned short*)(ws + 67108864);
  unsigned short* Kb     = (unsigned short*)(ws + 130023424);
  unsigned short* ctxb   = (unsigned short*)(ws + 67108864); // over dead Qb
  unsigned short* Vt     = (unsigned short*)(ws + 192937984);
  unsigned short* Wqkv   = (unsigned short*)(ws + 260046848);
  float*          biasQ  = (float*)(ws + 266338304);
  float*          pooled = (float*)(ws + 266349824);

  const float scaleQ = 0.0322748612183951f;  // 1/sqrt(960)

  cast_wqkv<<<2880, 256, 0, stream>>>(Wq, Wk, Wv, bq, bk, bv, Wqkv, biasQ, scaleQ);
  cast_x<<<8192, 256, 0, stream>>>(x, xb);

  // fused QKV: [32768 x 2880] = xb[32768x1024] . Wqkv^T; writes Qb, Kb, Vt(T)
  // mTiles=128 (32768/256), nTiles=23 (2944 B-rows <= 3072 alloc), K=1024
  gemm3r<1><<<128 * 23, 512, 0, stream>>>(
      xb, Wqkv, 1024, 1024, biasQ, nullptr, Qb, Kb, Vt,
      128, 23, 2880, 0, 0, 0, 0);

  attn_softmax<<<512, 512, 0, stream>>>(Qb, Kb, mask, P);

  // ctx[b] = P[b] . Vt[b]^T : M=1024 (4 tiles), N=960 (8 tiles pad 1024),
  // K=1024; bf16 out over dead Qb
  gemm3r<2><<<4 * 8 * 32, 512, 0, stream>>>(
      P, Vt, 1024, 1024, nullptr, ctxb, nullptr, nullptr, nullptr,
      4, 8, 960, 960, (size_t)1048576, (size_t)1048576, (size_t)983040);

  hipMemsetAsync(pooled, 0, 32 * 960 * 4, stream);
  ln_pool<<<dim3(32, 32), 256, 0, stream>>>(ctxb, x, mask, lng, lnb, pooled);
  mlp_head<<<32, 256, 0, stream>>>(pooled, mask, W1, b1, W2, b2, W3, b3, W4, b4, out);
}

// Round 8
// 545.223 us; speedup vs baseline: 1.3994x; 1.3199x over previous
//
#include <hip/hip_runtime.h>

// ---------------------------------------------------------------------------
// DeepProteinClassifier with mask-compaction:
//   masked rows are dead end-to-end (pooling skips masked q; masked k get
//   exp(-1e9)->0 exactly). Compact rows per batch (cnt[b]~512 of 1024):
//   scan_mask -> compact_x -> QKV gemm (per-b M=ceil128(cnt)) ->
//   attn (q-blocks < cnt, cols>=cnt -> -1e9) -> PV gemm (K=ceil64(cnt)) ->
//   LN+pool over compacted rows (residual gathered via idx) -> MLP.
// GEMM: R5's proven gemm128 (BK=64 dbuf, counted vmcnt(8), 0-conflict swizzle).
// ---------------------------------------------------------------------------

#define DEVINL __device__ __forceinline__

typedef __attribute__((ext_vector_type(8))) short bf16x8;
typedef __attribute__((ext_vector_type(4))) float f32x4;
typedef __attribute__((ext_vector_type(4))) unsigned short u16x4;

DEVINL unsigned short f2bf(float f) {
  unsigned int u = __float_as_uint(f);
  u += 0x7FFFu + ((u >> 16) & 1u);  // round-to-nearest-even
  return (unsigned short)(u >> 16);
}

DEVINL float bf2f(unsigned short h) { return __uint_as_float(((unsigned int)h) << 16); }

DEVINL void gload_lds16(const void* g, void* l) {
  __builtin_amdgcn_global_load_lds((const __attribute__((address_space(1))) unsigned int*)g,
                                   (__attribute__((address_space(3))) unsigned int*)l,
                                   16, 0, 0);
}

#define MFMA16(a, b, c) __builtin_amdgcn_mfma_f32_16x16x32_bf16((a), (b), (c), 0, 0, 0)

// ---------------------------------------------------------------------------
// Per-b prefix scan of mask: idx[b][j] = s of j-th unmasked row; cnt[b].
// One block of 256 per b; Hillis-Steele over 256 partials (4 elems/thread).
// ---------------------------------------------------------------------------
__global__ __launch_bounds__(256) void scan_mask(
    const int* __restrict__ mask, int* __restrict__ idx, int* __restrict__ cnt) {
  __shared__ int ps[256];
  const int b = blockIdx.x, t = threadIdx.x;
  const int4 m = *(const int4*)(mask + b * 1024 + t * 4);
  const int s = (m.x != 0) + (m.y != 0) + (m.z != 0) + (m.w != 0);
  ps[t] = s;
  __syncthreads();
  for (int off = 1; off < 256; off <<= 1) {
    const int v = (t >= off) ? ps[t - off] : 0;
    __syncthreads();
    ps[t] += v;
    __syncthreads();
  }
  int pos = ps[t] - s;
  if (m.x) idx[b * 1024 + pos++] = t * 4 + 0;
  if (m.y) idx[b * 1024 + pos++] = t * 4 + 1;
  if (m.z) idx[b * 1024 + pos++] = t * 4 + 2;
  if (m.w) idx[b * 1024 + pos++] = t * 4 + 3;
  if (t == 255) cnt[b] = ps[255];
}

// ---------------------------------------------------------------------------
// Build Wqkv [3072][1024] bf16 (rows 0..959 Wq*scale, 960..1919 Wk,
// 1920..2879 Wv; cols 960..1023 zero) and biasQKV[2880] f32.
// ---------------------------------------------------------------------------
__global__ __launch_bounds__(256) void cast_wqkv(
    const float* __restrict__ Wq, const float* __restrict__ Wk, const float* __restrict__ Wv,
    const float* __restrict__ bq, const float* __restrict__ bk, const float* __restrict__ bv,
    unsigned short* __restrict__ Wqkv, float* __restrict__ biasQ, float scaleQ) {
  const int r = blockIdx.x, t = threadIdx.x;
  const int seg = (r >= 1920) ? 2 : (r >= 960 ? 1 : 0);
  const int sr = r - seg * 960;
  const float* W = (seg == 0) ? Wq : (seg == 1) ? Wk : Wv;
  const float sc = (seg == 0) ? scaleQ : 1.0f;
  if (t < 240) {
    f32x4 v = *(const f32x4*)(W + (size_t)sr * 960 + t * 4);
    u16x4 o;
    o[0] = f2bf(v[0] * sc); o[1] = f2bf(v[1] * sc);
    o[2] = f2bf(v[2] * sc); o[3] = f2bf(v[3] * sc);
    *(u16x4*)(Wqkv + (size_t)r * 1024 + t * 4) = o;
  } else {
    u16x4 z = {};
    *(u16x4*)(Wqkv + (size_t)r * 1024 + 960 + (t - 240) * 4) = z;
  }
  if (t == 0) {
    const float* bb = (seg == 0) ? bq : (seg == 1) ? bk : bv;
    biasQ[r] = bb[sr] * sc;
  }
}

// ---------------------------------------------------------------------------
// Gather-compact-cast: xc[b][j] = bf16(x[b][idx[b][j]]) for j < cnt[b];
// zero rows j in [cnt, ceil128(cnt)); 1024 cols (960 data + 64 zero pad).
// grid (256 rowgroups, 32 b), 4 rows/block (wave per row).
// ---------------------------------------------------------------------------
__global__ __launch_bounds__(256) void compact_x(
    const float* __restrict__ x, const int* __restrict__ idx, const int* __restrict__ cnt,
    unsigned short* __restrict__ xc) {
  const int b = blockIdx.y;
  const int j = blockIdx.x * 4 + (threadIdx.x >> 6);
  const int l = threadIdx.x & 63;
  const int cb = cnt[b];
  const int cbc = (cb + 127) & ~127;
  if (j >= cbc) return;
  unsigned short* o = xc + ((size_t)b * 1024 + j) * 1024 + l * 16;
  bf16x8 o0 = {}, o1 = {};
  if (j < cb && l < 60) {
    const int s = idx[b * 1024 + j];
    const float* g = x + ((size_t)b * 1024 + s) * 960 + l * 16;
    f32x4 v0 = *(const f32x4*)(g);
    f32x4 v1 = *(const f32x4*)(g + 4);
    f32x4 v2 = *(const f32x4*)(g + 8);
    f32x4 v3 = *(const f32x4*)(g + 12);
    o0[0] = (short)f2bf(v0[0]); o0[1] = (short)f2bf(v0[1]);
    o0[2] = (short)f2bf(v0[2]); o0[3] = (short)f2bf(v0[3]);
    o0[4] = (short)f2bf(v1[0]); o0[5] = (short)f2bf(v1[1]);
    o0[6] = (short)f2bf(v1[2]); o0[7] = (short)f2bf(v1[3]);
    o1[0] = (short)f2bf(v2[0]); o1[1] = (short)f2bf(v2[1]);
    o1[2] = (short)f2bf(v2[2]); o1[3] = (short)f2bf(v2[3]);
    o1[4] = (short)f2bf(v3[0]); o1[5] = (short)f2bf(v3[1]);
    o1[6] = (short)f2bf(v3[2]); o1[7] = (short)f2bf(v3[3]);
  }
  *(bf16x8*)(o) = o0;
  *(bf16x8*)(o + 8) = o1;
}

// ---------------------------------------------------------------------------
// 128x128 NT GEMM (R5 structure, proven): BK=64, 4 waves (2x2), 64x64/wave,
// dbuf LDS (64KB -> 2 blocks/CU). Counted-vmcnt: STAGE(t+1) [8 gloads/thr],
// vmcnt(8), s_barrier, compute(t), s_barrier. (row&7) 16B-slot source XOR
// swizzle (measured 0 bank conflicts).
// Per-b compaction: zb = batch; exit if m0 >= cnt[zb].
// MODE 1: QKV epilogue (bf16 +bias -> Qb/Kb/Vt-transposed), nkt fixed.
// MODE 2: bf16 out (PV -> ctx), nkt = ceil64(cnt[zb]) (P cols >= cnt are
//         exactly 0, so truncation is bit-exact).
// Bijective XCD-chunked swizzle; n-tile fastest.
// ---------------------------------------------------------------------------
template <int MODE>
__global__ __launch_bounds__(256, 2) void gemm128(
    const unsigned short* __restrict__ Ap, const unsigned short* __restrict__ Bp,
    int lda, int ldb, const float* __restrict__ bias,
    unsigned short* __restrict__ outC, unsigned short* __restrict__ outQ,
    unsigned short* __restrict__ outK, unsigned short* __restrict__ outV,
    int mTiles, int nTiles, int nktFixed, int ncols, int ldo,
    size_t aStride, size_t bStride, size_t oStride, const int* __restrict__ cntArr) {
  __shared__ unsigned short As[2][128 * 64];
  __shared__ unsigned short Bs[2][128 * 64];
  const int t = threadIdx.x, l = t & 63, w = t >> 6;
  const int wr = w >> 1, wc = w & 1;
  const int lq = l & 15, lh = l >> 4;

  const int nwg = (int)gridDim.x;
  const int flat = (int)blockIdx.x;
  const int q8 = nwg >> 3, r8 = nwg & 7, xcd = flat & 7;
  const int wgid = (xcd < r8 ? xcd * (q8 + 1) : r8 * (q8 + 1) + (xcd - r8) * q8) + (flat >> 3);
  const int pt = mTiles * nTiles;
  const int zb = wgid / pt;
  const int rm = wgid - zb * pt;
  const int mi = rm / nTiles;
  const int m0 = mi * 128;
  const int n0 = (rm - mi * nTiles) * 128;

  const int cb = cntArr[zb];
  if (m0 >= cb) return;  // tile fully beyond this batch's compacted rows
  const int nkt = (MODE == 2) ? ((cb + 63) >> 6) : nktFixed;

  const unsigned short* A = Ap + (size_t)zb * aStride + (size_t)m0 * lda;
  const unsigned short* B = Bp + (size_t)zb * bStride + (size_t)n0 * ldb;

#define STAGEG(D0, BB)                                                        \
  {                                                                           \
    _Pragma("unroll") for (int q_ = 0; q_ < 4; ++q_) {                        \
      const int r_ = q_ * 32 + w * 8 + (l >> 3);                              \
      const int sg_ = (l & 7) ^ (r_ & 7);                                     \
      gload_lds16(A + (size_t)r_ * lda + (D0) + sg_ * 8,                      \
                  (char*)&As[BB][(size_t)(q_ * 32 + w * 8) * 64]);            \
      gload_lds16(B + (size_t)r_ * ldb + (D0) + sg_ * 8,                      \
                  (char*)&Bs[BB][(size_t)(q_ * 32 + w * 8) * 64]);            \
    }                                                                         \
  }

  f32x4 acc[4][4] = {};
  STAGEG(0, 0);
  int buf = 0;
  for (int kt = 0; kt < nkt; ++kt) {
    if (kt + 1 < nkt) {
      STAGEG((kt + 1) * 64, buf ^ 1);
      asm volatile("s_waitcnt vmcnt(8)" ::: "memory");  // tile kt landed; kt+1 in flight
    } else {
      asm volatile("s_waitcnt vmcnt(0)" ::: "memory");
    }
    __builtin_amdgcn_sched_barrier(0);
    __builtin_amdgcn_s_barrier();
    bf16x8 aF[2][4], bF[2][4];
#pragma unroll
    for (int h = 0; h < 2; ++h)
#pragma unroll
      for (int i = 0; i < 4; ++i) {
        const int rowA = 64 * wr + 16 * i + lq;
        aF[h][i] = *(const bf16x8*)&As[buf][(size_t)rowA * 64 +
                                           (size_t)(((h << 2) | lh) ^ (rowA & 7)) * 8];
        const int rowB = 64 * wc + 16 * i + lq;
        bF[h][i] = *(const bf16x8*)&Bs[buf][(size_t)rowB * 64 +
                                           (size_t)(((h << 2) | lh) ^ (rowB & 7)) * 8];
      }
#pragma unroll
    for (int h = 0; h < 2; ++h)
#pragma unroll
      for (int i = 0; i < 4; ++i)
#pragma unroll
        for (int j = 0; j < 4; ++j) acc[i][j] = MFMA16(aF[h][i], bF[h][j], acc[i][j]);
    __builtin_amdgcn_s_barrier();
    buf ^= 1;
  }
#undef STAGEG

  // epilogue: C/D layout col = lane&15, row = (lane>>4)*4 + reg
  if (MODE == 2) {  // bf16 ctx out, per-b compacted rows
#pragma unroll
    for (int j = 0; j < 4; ++j) {
      const int col = n0 + 64 * wc + 16 * j + lq;
      if (col >= ncols) continue;
#pragma unroll
      for (int i = 0; i < 4; ++i)
#pragma unroll
        for (int r = 0; r < 4; ++r) {
          const int row = m0 + 64 * wr + 16 * i + 4 * lh + r;
          outC[(size_t)zb * oStride + (size_t)row * ldo + col] = f2bf(acc[i][j][r]);
        }
    }
  } else {  // MODE 1: QKV split epilogue (rows are per-b compacted indices)
#pragma unroll
    for (int j = 0; j < 4; ++j) {
      const int col = n0 + 64 * wc + 16 * j + lq;
      if (col >= ncols) continue;
      const int seg = (col >= 1920) ? 2 : (col >= 960 ? 1 : 0);
      const int dcol = col - seg * 960;
      const float bv = bias[col];
#pragma unroll
      for (int i = 0; i < 4; ++i)
#pragma unroll
        for (int r = 0; r < 4; ++r) {
          const int row = m0 + 64 * wr + 16 * i + 4 * lh + r;  // j within b
          const unsigned short v = f2bf(acc[i][j][r] + bv);
          if (seg == 0) outQ[((size_t)zb * 1024 + row) * 960 + dcol] = v;
          else if (seg == 1) outK[((size_t)zb * 1024 + row) * 960 + dcol] = v;
          else outV[((size_t)zb << 20) + ((size_t)dcol << 10) + row] = v;
        }
    }
  }
}

// ---------------------------------------------------------------------------
// Fused scores + masked softmax over COMPACTED rows (counted-vmcnt pipeline).
// Block = 64 q-rows x 1024 k-cols of one b; exit if q0 >= cnt[b];
// k-cols >= cnt[b] -> -1e9 (exp -> exactly 0).
// ---------------------------------------------------------------------------
__global__ __launch_bounds__(512, 2) void attn_softmax(
    const unsigned short* __restrict__ Qb, const unsigned short* __restrict__ Kb,
    const int* __restrict__ cnt, unsigned short* __restrict__ P) {
  __shared__ unsigned short Ks[2][1024 * 32];
  __shared__ unsigned short Qs[2][64 * 32];
  __shared__ float red[2][8][64];
  const int t = threadIdx.x, l = t & 63, w = t >> 6;
  const int flat = blockIdx.x;
  const int b = (flat & 7) * 4 + ((flat >> 3) >> 4);
  const int q0 = ((flat >> 3) & 15) * 64;
  const int cb = cnt[b];
  if (q0 >= cb) return;
  const int lq = l & 15, lh = l >> 4;
  const size_t kbase = (size_t)b * 1024 * 960;
  const size_t qbase = ((size_t)b * 1024 + q0) * 960;
  const int lr = l >> 2, sg0 = l & 3;

#define STAGE(kkv, bufv)                                                      \
  {                                                                           \
    const int d0_ = (kkv) * 32;                                               \
    _Pragma("unroll") for (int i_ = 0; i_ < 8; ++i_) {                        \
      const int br_ = i_ * 128 + w * 16;                                      \
      const int kr_ = br_ + lr;                                               \
      const int sg_ = sg0 ^ ((kr_ >> 1) & 3);                                 \
      gload_lds16(Kb + kbase + (size_t)kr_ * 960 + d0_ + sg_ * 8,             \
                  (char*)Ks[(bufv)] + (size_t)br_ * 64);                      \
    }                                                                         \
    {                                                                         \
      const int qw_ = w & 3;                                                  \
      const int qr_ = qw_ * 16 + lr;                                          \
      const int sg_ = sg0 ^ ((qr_ >> 1) & 3);                                 \
      gload_lds16(Qb + qbase + (size_t)qr_ * 960 + d0_ + sg_ * 8,             \
                  (char*)Qs[(bufv)] + (size_t)(qw_ * 16) * 64);               \
    }                                                                         \
  }

  f32x4 acc[4][8] = {};
  STAGE(0, 0);
  int buf = 0;
  for (int kk = 0; kk < 30; ++kk) {
    if (kk < 29) {
      STAGE(kk + 1, buf ^ 1);
      asm volatile("s_waitcnt vmcnt(9)" ::: "memory");
    } else {
      asm volatile("s_waitcnt vmcnt(0)" ::: "memory");
    }
    __builtin_amdgcn_sched_barrier(0);
    __builtin_amdgcn_s_barrier();
    bf16x8 aF[4], bF[8];
#pragma unroll
    for (int i = 0; i < 4; ++i) {
      const int qr = 16 * i + lq;
      aF[i] = *(const bf16x8*)(Qs[buf] + qr * 32 + (lh ^ ((qr >> 1) & 3)) * 8);
    }
#pragma unroll
    for (int j = 0; j < 8; ++j) {
      const int kr = 128 * w + 16 * j + lq;
      bF[j] = *(const bf16x8*)(Ks[buf] + kr * 32 + (lh ^ ((kr >> 1) & 3)) * 8);
    }
#pragma unroll
    for (int i = 0; i < 4; ++i)
#pragma unroll
      for (int j = 0; j < 8; ++j) acc[i][j] = MFMA16(aF[i], bF[j], acc[i][j]);
    __builtin_amdgcn_s_barrier();
    buf ^= 1;
  }
#undef STAGE

  // compacted cols >= cnt -> -1e9 (assignment also scrubs any stale-NaN cols)
#pragma unroll
  for (int j = 0; j < 8; ++j) {
    const int k = 128 * w + 16 * j + lq;
    if (k >= cb) {
#pragma unroll
      for (int i = 0; i < 4; ++i)
#pragma unroll
        for (int r = 0; r < 4; ++r) acc[i][j][r] = -1e9f;
    }
  }

  float rmax[4][4];
#pragma unroll
  for (int i = 0; i < 4; ++i)
#pragma unroll
    for (int r = 0; r < 4; ++r) {
      float m = acc[i][0][r];
#pragma unroll
      for (int j = 1; j < 8; ++j) m = fmaxf(m, acc[i][j][r]);
      m = fmaxf(m, __shfl_xor(m, 1));
      m = fmaxf(m, __shfl_xor(m, 2));
      m = fmaxf(m, __shfl_xor(m, 4));
      m = fmaxf(m, __shfl_xor(m, 8));
      rmax[i][r] = m;
    }
  if (lq == 0) {
#pragma unroll
    for (int i = 0; i < 4; ++i)
#pragma unroll
      for (int r = 0; r < 4; ++r) red[0][w][16 * i + 4 * lh + r] = rmax[i][r];
  }
  __syncthreads();
#pragma unroll
  for (int i = 0; i < 4; ++i)
#pragma unroll
    for (int r = 0; r < 4; ++r) {
      const int rowi = 16 * i + 4 * lh + r;
      float m = red[0][0][rowi];
#pragma unroll
      for (int w2 = 1; w2 < 8; ++w2) m = fmaxf(m, red[0][w2][rowi]);
      rmax[i][r] = m;
    }

  float rsum[4][4];
#pragma unroll
  for (int i = 0; i < 4; ++i)
#pragma unroll
    for (int r = 0; r < 4; ++r) {
      float s = 0.f;
#pragma unroll
      for (int j = 0; j < 8; ++j) {
        const float e = __expf(acc[i][j][r] - rmax[i][r]);
        acc[i][j][r] = e;
        s += e;
      }
      s += __shfl_xor(s, 1); s += __shfl_xor(s, 2);
      s += __shfl_xor(s, 4); s += __shfl_xor(s, 8);
      rsum[i][r] = s;
    }
  if (lq == 0) {
#pragma unroll
    for (int i = 0; i < 4; ++i)
#pragma unroll
      for (int r = 0; r < 4; ++r) red[1][w][16 * i + 4 * lh + r] = rsum[i][r];
  }
  __syncthreads();

  const size_t pb = ((size_t)b << 20) + (size_t)q0 * 1024;
#pragma unroll
  for (int i = 0; i < 4; ++i)
#pragma unroll
    for (int r = 0; r < 4; ++r) {
      const int rowi = 16 * i + 4 * lh + r;
      float s = 0.f;
#pragma unroll
      for (int w2 = 0; w2 < 8; ++w2) s += red[1][w2][rowi];
      const float inv = 1.0f / s;
#pragma unroll
      for (int j = 0; j < 8; ++j) {
        const int col = 128 * w + 16 * j + lq;
        P[pb + (size_t)rowi * 1024 + col] = f2bf(acc[i][j][r] * inv);
      }
    }
}

// ---------------------------------------------------------------------------
// Compacted LN+pool: for j < cnt[b]: h = bf16(ctx[b][j]) + x[b][idx[b][j]];
// LayerNorm(h)*g+b; pooled[b] += (atomics).
// ---------------------------------------------------------------------------
__global__ __launch_bounds__(256) void ln_pool(
    const unsigned short* __restrict__ ctxb, const float* __restrict__ x,
    const int* __restrict__ idx, const int* __restrict__ cnt,
    const float* __restrict__ g, const float* __restrict__ bta,
    float* __restrict__ pooled) {
  const int b = blockIdx.y, chunk = blockIdx.x;
  const int w = threadIdx.x >> 6, l = threadIdx.x & 63;
  const int cb = cnt[b];
  f32x4 gc[4], bc[4];
#pragma unroll
  for (int c = 0; c < 4; ++c) {
    const int i4 = c * 64 + l;
    if (i4 < 240) {
      gc[c] = *(const f32x4*)(g + i4 * 4);
      bc[c] = *(const f32x4*)(bta + i4 * 4);
    }
  }
  f32x4 accp[4] = {};
  for (int rr = 0; rr < 8; ++rr) {
    const int j = chunk * 32 + w * 8 + rr;
    if (j >= cb) continue;  // wave-uniform
    const int sidx = idx[b * 1024 + j];
    const size_t cbase = ((size_t)b * 1024 + j) * 960;
    const size_t xbase = ((size_t)b * 1024 + sidx) * 960;
    f32x4 h[4];
    float part = 0.f;
#pragma unroll
    for (int c = 0; c < 4; ++c) {
      const int i4 = c * 64 + l;
      if (i4 < 240) {
        u16x4 cv = *(const u16x4*)(ctxb + cbase + (size_t)i4 * 4);
        f32x4 xv = *(const f32x4*)(x + xbase + (size_t)i4 * 4);
        h[c][0] = bf2f(cv[0]) + xv[0];
        h[c][1] = bf2f(cv[1]) + xv[1];
        h[c][2] = bf2f(cv[2]) + xv[2];
        h[c][3] = bf2f(cv[3]) + xv[3];
        part += h[c][0] + h[c][1] + h[c][2] + h[c][3];
      } else {
        h[c] = 0;
      }
    }
#pragma unroll
    for (int o = 1; o < 64; o <<= 1) part += __shfl_xor(part, o);
    const float mu = part * (1.0f / 960.0f);
    float p2 = 0.f;
#pragma unroll
    for (int c = 0; c < 4; ++c) {
      if (c * 64 + l < 240) {
#pragma unroll
        for (int k2 = 0; k2 < 4; ++k2) {
          const float d = h[c][k2] - mu;
          p2 += d * d;
        }
      }
    }
#pragma unroll
    for (int o = 1; o < 64; o <<= 1) p2 += __shfl_xor(p2, o);
    const float rs = rsqrtf(p2 * (1.0f / 960.0f) + 1e-5f);
#pragma unroll
    for (int c = 0; c < 4; ++c) {
      if (c * 64 + l < 240) {
#pragma unroll
        for (int k2 = 0; k2 < 4; ++k2)
          accp[c][k2] += (h[c][k2] - mu) * rs * gc[c][k2] + bc[c][k2];
      }
    }
  }
#pragma unroll
  for (int c = 0; c < 4; ++c) {
    const int i4 = c * 64 + l;
    if (i4 < 240) {
#pragma unroll
      for (int k2 = 0; k2 < 4; ++k2) atomicAdd(&pooled[b * 960 + i4 * 4 + k2], accp[c][k2]);
    }
  }
}

// ---------------------------------------------------------------------------
// pooled/cnt -> 960-512-256-128-10 MLP fp32. One block per batch row.
// ---------------------------------------------------------------------------
__global__ __launch_bounds__(256) void mlp_head(
    const float* __restrict__ pooled, const int* __restrict__ cnt,
    const float* __restrict__ W1, const float* __restrict__ b1,
    const float* __restrict__ W2, const float* __restrict__ b2,
    const float* __restrict__ W3, const float* __restrict__ b3,
    const float* __restrict__ W4, const float* __restrict__ b4, float* __restrict__ out) {
  __shared__ float h0[960], h1[512], h2[256], h3[128];
  const int b = blockIdx.x, t = threadIdx.x;
  const float inv = 1.0f / fmaxf((float)cnt[b], 1e-9f);
  for (int d = t; d < 960; d += 256) h0[d] = pooled[b * 960 + d] * inv;
  __syncthreads();
  for (int o = t; o < 512; o += 256) {
    float a = b1[o];
    const float* wr = W1 + (size_t)o * 960;
    for (int k = 0; k < 960; k += 4) {
      f32x4 wv = *(const f32x4*)(wr + k);
      f32x4 hv = *(const f32x4*)(h0 + k);
      a += wv[0] * hv[0] + wv[1] * hv[1] + wv[2] * hv[2] + wv[3] * hv[3];
    }
    h1[o] = fmaxf(a, 0.f);
  }
  __syncthreads();
  {
    float a = b2[t];
    const float* wr = W2 + (size_t)t * 512;
    for (int k = 0; k < 512; k += 4) {
      f32x4 wv = *(const f32x4*)(wr + k);
      f32x4 hv = *(const f32x4*)(h1 + k);
      a += wv[0] * hv[0] + wv[1] * hv[1] + wv[2] * hv[2] + wv[3] * hv[3];
    }
    h2[t] = fmaxf(a, 0.f);
  }
  __syncthreads();
  if (t < 128) {
    float a = b3[t];
    const float* wr = W3 + (size_t)t * 256;
    for (int k = 0; k < 256; k += 4) {
      f32x4 wv = *(const f32x4*)(wr + k);
      f32x4 hv = *(const f32x4*)(h2 + k);
      a += wv[0] * hv[0] + wv[1] * hv[1] + wv[2] * hv[2] + wv[3] * hv[3];
    }
    h3[t] = fmaxf(a, 0.f);
  }
  __syncthreads();
  if (t < 10) {
    float a = b4[t];
    const float* wr = W4 + (size_t)t * 128;
    for (int k = 0; k < 128; ++k) a += wr[k] * h3[k];
    out[b * 10 + t] = a;
  }
}

// ---------------------------------------------------------------------------
// Workspace (bytes):
//   [0,          67108864)  xc bf16 [32][1024][1024] -> P bf16 [32][1024][1024]
//   [67108864,  130023424)  Qb bf16 [32][1024][960]  -> ctx bf16 [32][1024][960]
//   [130023424, 192937984)  Kb bf16 [32][1024][960]
//   [192937984, 260046848)  Vt bf16 [32][1024][1024]
//   [260046848, 266338304)  Wqkv bf16 [3072][1024]
//   [266338304, 266349824)  biasQKV f32 [2880]
//   [266349824, 266472704)  pooled f32 [32][960]
//   [266472704, 266472832)  cnt i32 [32]
//   [266472832, 266603904)  idx i32 [32][1024]
// ---------------------------------------------------------------------------
extern "C" void kernel_launch(void* const* d_in, const int* in_sizes, int n_in,
                              void* d_out, int out_size, void* d_ws, size_t ws_size,
                              hipStream_t stream) {
  (void)in_sizes; (void)n_in; (void)out_size; (void)ws_size;
  const float* x    = (const float*)d_in[0];
  const int*   mask = (const int*)d_in[1];
  const float* Wq   = (const float*)d_in[2];
  const float* bq   = (const float*)d_in[3];
  const float* Wk   = (const float*)d_in[4];
  const float* bk   = (const float*)d_in[5];
  const float* Wv   = (const float*)d_in[6];
  const float* bv   = (const float*)d_in[7];
  const float* lng  = (const float*)d_in[8];
  const float* lnb  = (const float*)d_in[9];
  const float* W1   = (const float*)d_in[10];
  const float* b1   = (const float*)d_in[11];
  const float* W2   = (const float*)d_in[12];
  const float* b2   = (const float*)d_in[13];
  const float* W3   = (const float*)d_in[14];
  const float* b3   = (const float*)d_in[15];
  const float* W4   = (const float*)d_in[16];
  const float* b4   = (const float*)d_in[17];
  float* out = (float*)d_out;

  char* ws = (char*)d_ws;
  unsigned short* xc     = (unsigned short*)(ws);
  unsigned short* P      = (unsigned short*)(ws);            // over dead xc
  unsigned short* Qb     = (unsigned short*)(ws + 67108864);
  unsigned short* Kb     = (unsigned short*)(ws + 130023424);
  unsigned short* ctxb   = (unsigned short*)(ws + 67108864); // over dead Qb
  unsigned short* Vt     = (unsigned short*)(ws + 192937984);
  unsigned short* Wqkv   = (unsigned short*)(ws + 260046848);
  float*          biasQ  = (float*)(ws + 266338304);
  float*          pooled = (float*)(ws + 266349824);
  int*            cntW   = (int*)(ws + 266472704);
  int*            idxW   = (int*)(ws + 266472832);

  const float scaleQ = 0.0322748612183951f;  // 1/sqrt(960)

  scan_mask<<<32, 256, 0, stream>>>(mask, idxW, cntW);
  cast_wqkv<<<2880, 256, 0, stream>>>(Wq, Wk, Wv, bq, bk, bv, Wqkv, biasQ, scaleQ);
  compact_x<<<dim3(256, 32), 256, 0, stream>>>(x, idxW, cntW, xc);

  // fused QKV over compacted rows: per b, M = ceil128(cnt[b]) (early-exit),
  // N = 2880 (23 tiles), K = 960 (15 K-tiles; cols 960.. are zero anyway)
  gemm128<1><<<32 * 8 * 23, 256, 0, stream>>>(
      xc, Wqkv, 1024, 1024, biasQ, nullptr, Qb, Kb, Vt,
      8, 23, 15, 2880, 0, (size_t)1048576, 0, 0, cntW);

  attn_softmax<<<512, 512, 0, stream>>>(Qb, Kb, cntW, P);

  // ctx[b] = P[b] . Vt[b]^T : M = ceil128(cnt) (exit), N=960, K = ceil64(cnt)
  gemm128<2><<<8 * 8 * 32, 256, 0, stream>>>(
      P, Vt, 1024, 1024, nullptr, ctxb, nullptr, nullptr, nullptr,
      8, 8, 0, 960, 960, (size_t)1048576, (size_t)1048576, (size_t)983040, cntW);

  hipMemsetAsync(pooled, 0, 32 * 960 * 4, stream);
  ln_pool<<<dim3(32, 32), 256, 0, stream>>>(ctxb, x, idxW, cntW, lng, lnb, pooled);
  mlp_head<<<32, 256, 0, stream>>>(pooled, cntW, W1, b1, W2, b2, W3, b3, W4, b4, out);
}

// Round 9
// 514.515 us; speedup vs baseline: 1.4829x; 1.0597x over previous
//
#include <hip/hip_runtime.h>

// ---------------------------------------------------------------------------
// DeepProteinClassifier with mask-compaction + attn strip-skip:
//   scan_mask -> compact_x -> QKV gemm (per-b M=ceil128(cnt)) ->
//   attn (k work limited to nks=ceil128(cnt) strips; dead strips dummy-staged
//   to keep the vmcnt ledger; dead waves skip compute) ->
//   PV gemm (K=ceil64(cnt)) -> LN+pool -> MLP.
// GEMM: R5's proven gemm128 (BK=64 dbuf, counted vmcnt(8), 0-conflict swizzle).
// ---------------------------------------------------------------------------

#define DEVINL __device__ __forceinline__

typedef __attribute__((ext_vector_type(8))) short bf16x8;
typedef __attribute__((ext_vector_type(4))) float f32x4;
typedef __attribute__((ext_vector_type(4))) unsigned short u16x4;

DEVINL unsigned short f2bf(float f) {
  unsigned int u = __float_as_uint(f);
  u += 0x7FFFu + ((u >> 16) & 1u);  // round-to-nearest-even
  return (unsigned short)(u >> 16);
}

DEVINL float bf2f(unsigned short h) { return __uint_as_float(((unsigned int)h) << 16); }

DEVINL void gload_lds16(const void* g, void* l) {
  __builtin_amdgcn_global_load_lds((const __attribute__((address_space(1))) unsigned int*)g,
                                   (__attribute__((address_space(3))) unsigned int*)l,
                                   16, 0, 0);
}

#define MFMA16(a, b, c) __builtin_amdgcn_mfma_f32_16x16x32_bf16((a), (b), (c), 0, 0, 0)

// ---------------------------------------------------------------------------
// Per-b prefix scan of mask: idx[b][j] = s of j-th unmasked row; cnt[b].
// ---------------------------------------------------------------------------
__global__ __launch_bounds__(256) void scan_mask(
    const int* __restrict__ mask, int* __restrict__ idx, int* __restrict__ cnt) {
  __shared__ int ps[256];
  const int b = blockIdx.x, t = threadIdx.x;
  const int4 m = *(const int4*)(mask + b * 1024 + t * 4);
  const int s = (m.x != 0) + (m.y != 0) + (m.z != 0) + (m.w != 0);
  ps[t] = s;
  __syncthreads();
  for (int off = 1; off < 256; off <<= 1) {
    const int v = (t >= off) ? ps[t - off] : 0;
    __syncthreads();
    ps[t] += v;
    __syncthreads();
  }
  int pos = ps[t] - s;
  if (m.x) idx[b * 1024 + pos++] = t * 4 + 0;
  if (m.y) idx[b * 1024 + pos++] = t * 4 + 1;
  if (m.z) idx[b * 1024 + pos++] = t * 4 + 2;
  if (m.w) idx[b * 1024 + pos++] = t * 4 + 3;
  if (t == 255) cnt[b] = ps[255];
}

// ---------------------------------------------------------------------------
// Build Wqkv [3072][1024] bf16 + biasQKV[2880] f32 (Q pre-scaled).
// ---------------------------------------------------------------------------
__global__ __launch_bounds__(256) void cast_wqkv(
    const float* __restrict__ Wq, const float* __restrict__ Wk, const float* __restrict__ Wv,
    const float* __restrict__ bq, const float* __restrict__ bk, const float* __restrict__ bv,
    unsigned short* __restrict__ Wqkv, float* __restrict__ biasQ, float scaleQ) {
  const int r = blockIdx.x, t = threadIdx.x;
  const int seg = (r >= 1920) ? 2 : (r >= 960 ? 1 : 0);
  const int sr = r - seg * 960;
  const float* W = (seg == 0) ? Wq : (seg == 1) ? Wk : Wv;
  const float sc = (seg == 0) ? scaleQ : 1.0f;
  if (t < 240) {
    f32x4 v = *(const f32x4*)(W + (size_t)sr * 960 + t * 4);
    u16x4 o;
    o[0] = f2bf(v[0] * sc); o[1] = f2bf(v[1] * sc);
    o[2] = f2bf(v[2] * sc); o[3] = f2bf(v[3] * sc);
    *(u16x4*)(Wqkv + (size_t)r * 1024 + t * 4) = o;
  } else {
    u16x4 z = {};
    *(u16x4*)(Wqkv + (size_t)r * 1024 + 960 + (t - 240) * 4) = z;
  }
  if (t == 0) {
    const float* bb = (seg == 0) ? bq : (seg == 1) ? bk : bv;
    biasQ[r] = bb[sr] * sc;
  }
}

// ---------------------------------------------------------------------------
// Gather-compact-cast: xc[b][j] = bf16(x[b][idx[b][j]]) for j < cnt[b];
// zero rows j in [cnt, ceil128(cnt)); 1024 cols (960 data + 64 zero pad).
// ---------------------------------------------------------------------------
__global__ __launch_bounds__(256) void compact_x(
    const float* __restrict__ x, const int* __restrict__ idx, const int* __restrict__ cnt,
    unsigned short* __restrict__ xc) {
  const int b = blockIdx.y;
  const int j = blockIdx.x * 4 + (threadIdx.x >> 6);
  const int l = threadIdx.x & 63;
  const int cb = cnt[b];
  const int cbc = (cb + 127) & ~127;
  if (j >= cbc) return;
  unsigned short* o = xc + ((size_t)b * 1024 + j) * 1024 + l * 16;
  bf16x8 o0 = {}, o1 = {};
  if (j < cb && l < 60) {
    const int s = idx[b * 1024 + j];
    const float* g = x + ((size_t)b * 1024 + s) * 960 + l * 16;
    f32x4 v0 = *(const f32x4*)(g);
    f32x4 v1 = *(const f32x4*)(g + 4);
    f32x4 v2 = *(const f32x4*)(g + 8);
    f32x4 v3 = *(const f32x4*)(g + 12);
    o0[0] = (short)f2bf(v0[0]); o0[1] = (short)f2bf(v0[1]);
    o0[2] = (short)f2bf(v0[2]); o0[3] = (short)f2bf(v0[3]);
    o0[4] = (short)f2bf(v1[0]); o0[5] = (short)f2bf(v1[1]);
    o0[6] = (short)f2bf(v1[2]); o0[7] = (short)f2bf(v1[3]);
    o1[0] = (short)f2bf(v2[0]); o1[1] = (short)f2bf(v2[1]);
    o1[2] = (short)f2bf(v2[2]); o1[3] = (short)f2bf(v2[3]);
    o1[4] = (short)f2bf(v3[0]); o1[5] = (short)f2bf(v3[1]);
    o1[6] = (short)f2bf(v3[2]); o1[7] = (short)f2bf(v3[3]);
  }
  *(bf16x8*)(o) = o0;
  *(bf16x8*)(o + 8) = o1;
}

// ---------------------------------------------------------------------------
// 128x128 NT GEMM (R5 structure, proven). Per-b compaction via cntArr.
// MODE 1: QKV epilogue.  MODE 2: bf16 out, nkt = ceil64(cnt[zb]).
// ---------------------------------------------------------------------------
template <int MODE>
__global__ __launch_bounds__(256, 2) void gemm128(
    const unsigned short* __restrict__ Ap, const unsigned short* __restrict__ Bp,
    int lda, int ldb, const float* __restrict__ bias,
    unsigned short* __restrict__ outC, unsigned short* __restrict__ outQ,
    unsigned short* __restrict__ outK, unsigned short* __restrict__ outV,
    int mTiles, int nTiles, int nktFixed, int ncols, int ldo,
    size_t aStride, size_t bStride, size_t oStride, const int* __restrict__ cntArr) {
  __shared__ unsigned short As[2][128 * 64];
  __shared__ unsigned short Bs[2][128 * 64];
  const int t = threadIdx.x, l = t & 63, w = t >> 6;
  const int wr = w >> 1, wc = w & 1;
  const int lq = l & 15, lh = l >> 4;

  const int nwg = (int)gridDim.x;
  const int flat = (int)blockIdx.x;
  const int q8 = nwg >> 3, r8 = nwg & 7, xcd = flat & 7;
  const int wgid = (xcd < r8 ? xcd * (q8 + 1) : r8 * (q8 + 1) + (xcd - r8) * q8) + (flat >> 3);
  const int pt = mTiles * nTiles;
  const int zb = wgid / pt;
  const int rm = wgid - zb * pt;
  const int mi = rm / nTiles;
  const int m0 = mi * 128;
  const int n0 = (rm - mi * nTiles) * 128;

  const int cb = cntArr[zb];
  if (m0 >= cb) return;
  const int nkt = (MODE == 2) ? ((cb + 63) >> 6) : nktFixed;

  const unsigned short* A = Ap + (size_t)zb * aStride + (size_t)m0 * lda;
  const unsigned short* B = Bp + (size_t)zb * bStride + (size_t)n0 * ldb;

#define STAGEG(D0, BB)                                                        \
  {                                                                           \
    _Pragma("unroll") for (int q_ = 0; q_ < 4; ++q_) {                        \
      const int r_ = q_ * 32 + w * 8 + (l >> 3);                              \
      const int sg_ = (l & 7) ^ (r_ & 7);                                     \
      gload_lds16(A + (size_t)r_ * lda + (D0) + sg_ * 8,                      \
                  (char*)&As[BB][(size_t)(q_ * 32 + w * 8) * 64]);            \
      gload_lds16(B + (size_t)r_ * ldb + (D0) + sg_ * 8,                      \
                  (char*)&Bs[BB][(size_t)(q_ * 32 + w * 8) * 64]);            \
    }                                                                         \
  }

  f32x4 acc[4][4] = {};
  STAGEG(0, 0);
  int buf = 0;
  for (int kt = 0; kt < nkt; ++kt) {
    if (kt + 1 < nkt) {
      STAGEG((kt + 1) * 64, buf ^ 1);
      asm volatile("s_waitcnt vmcnt(8)" ::: "memory");
    } else {
      asm volatile("s_waitcnt vmcnt(0)" ::: "memory");
    }
    __builtin_amdgcn_sched_barrier(0);
    __builtin_amdgcn_s_barrier();
    bf16x8 aF[2][4], bF[2][4];
#pragma unroll
    for (int h = 0; h < 2; ++h)
#pragma unroll
      for (int i = 0; i < 4; ++i) {
        const int rowA = 64 * wr + 16 * i + lq;
        aF[h][i] = *(const bf16x8*)&As[buf][(size_t)rowA * 64 +
                                           (size_t)(((h << 2) | lh) ^ (rowA & 7)) * 8];
        const int rowB = 64 * wc + 16 * i + lq;
        bF[h][i] = *(const bf16x8*)&Bs[buf][(size_t)rowB * 64 +
                                           (size_t)(((h << 2) | lh) ^ (rowB & 7)) * 8];
      }
#pragma unroll
    for (int h = 0; h < 2; ++h)
#pragma unroll
      for (int i = 0; i < 4; ++i)
#pragma unroll
        for (int j = 0; j < 4; ++j) acc[i][j] = MFMA16(aF[h][i], bF[h][j], acc[i][j]);
    __builtin_amdgcn_s_barrier();
    buf ^= 1;
  }
#undef STAGEG

  if (MODE == 2) {
#pragma unroll
    for (int j = 0; j < 4; ++j) {
      const int col = n0 + 64 * wc + 16 * j + lq;
      if (col >= ncols) continue;
#pragma unroll
      for (int i = 0; i < 4; ++i)
#pragma unroll
        for (int r = 0; r < 4; ++r) {
          const int row = m0 + 64 * wr + 16 * i + 4 * lh + r;
          outC[(size_t)zb * oStride + (size_t)row * ldo + col] = f2bf(acc[i][j][r]);
        }
    }
  } else {
#pragma unroll
    for (int j = 0; j < 4; ++j) {
      const int col = n0 + 64 * wc + 16 * j + lq;
      if (col >= ncols) continue;
      const int seg = (col >= 1920) ? 2 : (col >= 960 ? 1 : 0);
      const int dcol = col - seg * 960;
      const float bv = bias[col];
#pragma unroll
      for (int i = 0; i < 4; ++i)
#pragma unroll
        for (int r = 0; r < 4; ++r) {
          const int row = m0 + 64 * wr + 16 * i + 4 * lh + r;
          const unsigned short v = f2bf(acc[i][j][r] + bv);
          if (seg == 0) outQ[((size_t)zb * 1024 + row) * 960 + dcol] = v;
          else if (seg == 1) outK[((size_t)zb * 1024 + row) * 960 + dcol] = v;
          else outV[((size_t)zb << 20) + ((size_t)dcol << 10) + row] = v;
        }
    }
  }
}

// ---------------------------------------------------------------------------
// Fused scores + masked softmax over COMPACTED rows, with STRIP-SKIP:
// nks = ceil128(cnt) active 128-col strips. Dead strips (i_ >= nks) are
// dummy-staged from strip 0 (same addr -> L1 hit) to keep 9 loads/wave so
// vmcnt(9) stays exact. Waves w >= nks skip all ds_reads/MFMAs (wave-uniform)
// and the P write (their cols >= 128*nks >= ceil64(cnt) are never read by PV).
// ---------------------------------------------------------------------------
__global__ __launch_bounds__(512, 2) void attn_softmax(
    const unsigned short* __restrict__ Qb, const unsigned short* __restrict__ Kb,
    const int* __restrict__ cnt, unsigned short* __restrict__ P) {
  __shared__ unsigned short Ks[2][1024 * 32];
  __shared__ unsigned short Qs[2][64 * 32];
  __shared__ float red[2][8][64];
  const int t = threadIdx.x, l = t & 63, w = t >> 6;
  const int flat = blockIdx.x;
  const int b = (flat & 7) * 4 + ((flat >> 3) >> 4);
  const int q0 = ((flat >> 3) & 15) * 64;
  const int cb = cnt[b];
  if (q0 >= cb) return;
  const int nks = (cb + 127) >> 7;  // active strips (1..8)
  const int lq = l & 15, lh = l >> 4;
  const size_t kbase = (size_t)b * 1024 * 960;
  const size_t qbase = ((size_t)b * 1024 + q0) * 960;
  const int lr = l >> 2, sg0 = l & 3;

#define STAGE(kkv, bufv)                                                      \
  {                                                                           \
    const int d0_ = (kkv) * 32;                                               \
    _Pragma("unroll") for (int i_ = 0; i_ < 8; ++i_) {                        \
      const int br_ = i_ * 128 + w * 16;                                      \
      const int kr_ = (i_ < nks) ? (br_ + lr) : (w * 16 + lr);                \
      const int sg_ = sg0 ^ ((kr_ >> 1) & 3);                                 \
      gload_lds16(Kb + kbase + (size_t)kr_ * 960 + d0_ + sg_ * 8,             \
                  (char*)Ks[(bufv)] + (size_t)br_ * 64);                      \
    }                                                                         \
    {                                                                         \
      const int qw_ = w & 3;                                                  \
      const int qr_ = qw_ * 16 + lr;                                          \
      const int sg_ = sg0 ^ ((qr_ >> 1) & 3);                                 \
      gload_lds16(Qb + qbase + (size_t)qr_ * 960 + d0_ + sg_ * 8,             \
                  (char*)Qs[(bufv)] + (size_t)(qw_ * 16) * 64);               \
    }                                                                         \
  }

  f32x4 acc[4][8] = {};
  STAGE(0, 0);
  int buf = 0;
  for (int kk = 0; kk < 30; ++kk) {
    if (kk < 29) {
      STAGE(kk + 1, buf ^ 1);
      asm volatile("s_waitcnt vmcnt(9)" ::: "memory");
    } else {
      asm volatile("s_waitcnt vmcnt(0)" ::: "memory");
    }
    __builtin_amdgcn_sched_barrier(0);
    __builtin_amdgcn_s_barrier();
    if (w < nks) {  // wave-uniform: dead strips skip all compute
      bf16x8 aF[4], bF[8];
#pragma unroll
      for (int i = 0; i < 4; ++i) {
        const int qr = 16 * i + lq;
        aF[i] = *(const bf16x8*)(Qs[buf] + qr * 32 + (lh ^ ((qr >> 1) & 3)) * 8);
      }
#pragma unroll
      for (int j = 0; j < 8; ++j) {
        const int kr = 128 * w + 16 * j + lq;
        bF[j] = *(const bf16x8*)(Ks[buf] + kr * 32 + (lh ^ ((kr >> 1) & 3)) * 8);
      }
#pragma unroll
      for (int i = 0; i < 4; ++i)
#pragma unroll
        for (int j = 0; j < 8; ++j) acc[i][j] = MFMA16(aF[i], bF[j], acc[i][j]);
    }
    __builtin_amdgcn_s_barrier();
    buf ^= 1;
  }
#undef STAGE

  // compacted cols >= cnt -> -1e9 (covers dead waves entirely: acc was 0)
#pragma unroll
  for (int j = 0; j < 8; ++j) {
    const int k = 128 * w + 16 * j + lq;
    if (k >= cb) {
#pragma unroll
      for (int i = 0; i < 4; ++i)
#pragma unroll
        for (int r = 0; r < 4; ++r) acc[i][j][r] = -1e9f;
    }
  }

  float rmax[4][4];
#pragma unroll
  for (int i = 0; i < 4; ++i)
#pragma unroll
    for (int r = 0; r < 4; ++r) {
      float m = acc[i][0][r];
#pragma unroll
      for (int j = 1; j < 8; ++j) m = fmaxf(m, acc[i][j][r]);
      m = fmaxf(m, __shfl_xor(m, 1));
      m = fmaxf(m, __shfl_xor(m, 2));
      m = fmaxf(m, __shfl_xor(m, 4));
      m = fmaxf(m, __shfl_xor(m, 8));
      rmax[i][r] = m;
    }
  if (lq == 0) {
#pragma unroll
    for (int i = 0; i < 4; ++i)
#pragma unroll
      for (int r = 0; r < 4; ++r) red[0][w][16 * i + 4 * lh + r] = rmax[i][r];
  }
  __syncthreads();
#pragma unroll
  for (int i = 0; i < 4; ++i)
#pragma unroll
    for (int r = 0; r < 4; ++r) {
      const int rowi = 16 * i + 4 * lh + r;
      float m = red[0][0][rowi];
#pragma unroll
      for (int w2 = 1; w2 < 8; ++w2) m = fmaxf(m, red[0][w2][rowi]);
      rmax[i][r] = m;
    }

  float rsum[4][4];
#pragma unroll
  for (int i = 0; i < 4; ++i)
#pragma unroll
    for (int r = 0; r < 4; ++r) {
      float s = 0.f;
#pragma unroll
      for (int j = 0; j < 8; ++j) {
        const float e = __expf(acc[i][j][r] - rmax[i][r]);
        acc[i][j][r] = e;
        s += e;
      }
      s += __shfl_xor(s, 1); s += __shfl_xor(s, 2);
      s += __shfl_xor(s, 4); s += __shfl_xor(s, 8);
      rsum[i][r] = s;
    }
  if (lq == 0) {
#pragma unroll
    for (int i = 0; i < 4; ++i)
#pragma unroll
      for (int r = 0; r < 4; ++r) red[1][w][16 * i + 4 * lh + r] = rsum[i][r];
  }
  __syncthreads();

  if (w < nks) {  // dead waves' cols are never read by PV (>= ceil64(cnt))
    const size_t pb = ((size_t)b << 20) + (size_t)q0 * 1024;
#pragma unroll
    for (int i = 0; i < 4; ++i)
#pragma unroll
      for (int r = 0; r < 4; ++r) {
        const int rowi = 16 * i + 4 * lh + r;
        float s = 0.f;
#pragma unroll
        for (int w2 = 0; w2 < 8; ++w2) s += red[1][w2][rowi];
        const float inv = 1.0f / s;
#pragma unroll
        for (int j = 0; j < 8; ++j) {
          const int col = 128 * w + 16 * j + lq;
          P[pb + (size_t)rowi * 1024 + col] = f2bf(acc[i][j][r] * inv);
        }
      }
  }
}

// ---------------------------------------------------------------------------
// Compacted LN+pool.
// ---------------------------------------------------------------------------
__global__ __launch_bounds__(256) void ln_pool(
    const unsigned short* __restrict__ ctxb, const float* __restrict__ x,
    const int* __restrict__ idx, const int* __restrict__ cnt,
    const float* __restrict__ g, const float* __restrict__ bta,
    float* __restrict__ pooled) {
  const int b = blockIdx.y, chunk = blockIdx.x;
  const int w = threadIdx.x >> 6, l = threadIdx.x & 63;
  const int cb = cnt[b];
  f32x4 gc[4], bc[4];
#pragma unroll
  for (int c = 0; c < 4; ++c) {
    const int i4 = c * 64 + l;
    if (i4 < 240) {
      gc[c] = *(const f32x4*)(g + i4 * 4);
      bc[c] = *(const f32x4*)(bta + i4 * 4);
    }
  }
  f32x4 accp[4] = {};
  for (int rr = 0; rr < 8; ++rr) {
    const int j = chunk * 32 + w * 8 + rr;
    if (j >= cb) continue;
    const int sidx = idx[b * 1024 + j];
    const size_t cbase = ((size_t)b * 1024 + j) * 960;
    const size_t xbase = ((size_t)b * 1024 + sidx) * 960;
    f32x4 h[4];
    float part = 0.f;
#pragma unroll
    for (int c = 0; c < 4; ++c) {
      const int i4 = c * 64 + l;
      if (i4 < 240) {
        u16x4 cv = *(const u16x4*)(ctxb + cbase + (size_t)i4 * 4);
        f32x4 xv = *(const f32x4*)(x + xbase + (size_t)i4 * 4);
        h[c][0] = bf2f(cv[0]) + xv[0];
        h[c][1] = bf2f(cv[1]) + xv[1];
        h[c][2] = bf2f(cv[2]) + xv[2];
        h[c][3] = bf2f(cv[3]) + xv[3];
        part += h[c][0] + h[c][1] + h[c][2] + h[c][3];
      } else {
        h[c] = 0;
      }
    }
#pragma unroll
    for (int o = 1; o < 64; o <<= 1) part += __shfl_xor(part, o);
    const float mu = part * (1.0f / 960.0f);
    float p2 = 0.f;
#pragma unroll
    for (int c = 0; c < 4; ++c) {
      if (c * 64 + l < 240) {
#pragma unroll
        for (int k2 = 0; k2 < 4; ++k2) {
          const float d = h[c][k2] - mu;
          p2 += d * d;
        }
      }
    }
#pragma unroll
    for (int o = 1; o < 64; o <<= 1) p2 += __shfl_xor(p2, o);
    const float rs = rsqrtf(p2 * (1.0f / 960.0f) + 1e-5f);
#pragma unroll
    for (int c = 0; c < 4; ++c) {
      if (c * 64 + l < 240) {
#pragma unroll
        for (int k2 = 0; k2 < 4; ++k2)
          accp[c][k2] += (h[c][k2] - mu) * rs * gc[c][k2] + bc[c][k2];
      }
    }
  }
#pragma unroll
  for (int c = 0; c < 4; ++c) {
    const int i4 = c * 64 + l;
    if (i4 < 240) {
#pragma unroll
      for (int k2 = 0; k2 < 4; ++k2) atomicAdd(&pooled[b * 960 + i4 * 4 + k2], accp[c][k2]);
    }
  }
}

// ---------------------------------------------------------------------------
// pooled/cnt -> 960-512-256-128-10 MLP fp32.
// ---------------------------------------------------------------------------
__global__ __launch_bounds__(256) void mlp_head(
    const float* __restrict__ pooled, const int* __restrict__ cnt,
    const float* __restrict__ W1, const float* __restrict__ b1,
    const float* __restrict__ W2, const float* __restrict__ b2,
    const float* __restrict__ W3, const float* __restrict__ b3,
    const float* __restrict__ W4, const float* __restrict__ b4, float* __restrict__ out) {
  __shared__ float h0[960], h1[512], h2[256], h3[128];
  const int b = blockIdx.x, t = threadIdx.x;
  const float inv = 1.0f / fmaxf((float)cnt[b], 1e-9f);
  for (int d = t; d < 960; d += 256) h0[d] = pooled[b * 960 + d] * inv;
  __syncthreads();
  for (int o = t; o < 512; o += 256) {
    float a = b1[o];
    const float* wr = W1 + (size_t)o * 960;
    for (int k = 0; k < 960; k += 4) {
      f32x4 wv = *(const f32x4*)(wr + k);
      f32x4 hv = *(const f32x4*)(h0 + k);
      a += wv[0] * hv[0] + wv[1] * hv[1] + wv[2] * hv[2] + wv[3] * hv[3];
    }
    h1[o] = fmaxf(a, 0.f);
  }
  __syncthreads();
  {
    float a = b2[t];
    const float* wr = W2 + (size_t)t * 512;
    for (int k = 0; k < 512; k += 4) {
      f32x4 wv = *(const f32x4*)(wr + k);
      f32x4 hv = *(const f32x4*)(h1 + k);
      a += wv[0] * hv[0] + wv[1] * hv[1] + wv[2] * hv[2] + wv[3] * hv[3];
    }
    h2[t] = fmaxf(a, 0.f);
  }
  __syncthreads();
  if (t < 128) {
    float a = b3[t];
    const float* wr = W3 + (size_t)t * 256;
    for (int k = 0; k < 256; k += 4) {
      f32x4 wv = *(const f32x4*)(wr + k);
      f32x4 hv = *(const f32x4*)(h2 + k);
      a += wv[0] * hv[0] + wv[1] * hv[1] + wv[2] * hv[2] + wv[3] * hv[3];
    }
    h3[t] = fmaxf(a, 0.f);
  }
  __syncthreads();
  if (t < 10) {
    float a = b4[t];
    const float* wr = W4 + (size_t)t * 128;
    for (int k = 0; k < 128; ++k) a += wr[k] * h3[k];
    out[b * 10 + t] = a;
  }
}

// ---------------------------------------------------------------------------
// Workspace layout identical to round 8.
// ---------------------------------------------------------------------------
extern "C" void kernel_launch(void* const* d_in, const int* in_sizes, int n_in,
                              void* d_out, int out_size, void* d_ws, size_t ws_size,
                              hipStream_t stream) {
  (void)in_sizes; (void)n_in; (void)out_size; (void)ws_size;
  const float* x    = (const float*)d_in[0];
  const int*   mask = (const int*)d_in[1];
  const float* Wq   = (const float*)d_in[2];
  const float* bq   = (const float*)d_in[3];
  const float* Wk   = (const float*)d_in[4];
  const float* bk   = (const float*)d_in[5];
  const float* Wv   = (const float*)d_in[6];
  const float* bv   = (const float*)d_in[7];
  const float* lng  = (const float*)d_in[8];
  const float* lnb  = (const float*)d_in[9];
  const float* W1   = (const float*)d_in[10];
  const float* b1   = (const float*)d_in[11];
  const float* W2   = (const float*)d_in[12];
  const float* b2   = (const float*)d_in[13];
  const float* W3   = (const float*)d_in[14];
  const float* b3   = (const float*)d_in[15];
  const float* W4   = (const float*)d_in[16];
  const float* b4   = (const float*)d_in[17];
  float* out = (float*)d_out;

  char* ws = (char*)d_ws;
  unsigned short* xc     = (unsigned short*)(ws);
  unsigned short* P      = (unsigned short*)(ws);
  unsigned short* Qb     = (unsigned short*)(ws + 67108864);
  unsigned short* Kb     = (unsigned short*)(ws + 130023424);
  unsigned short* ctxb   = (unsigned short*)(ws + 67108864);
  unsigned short* Vt     = (unsigned short*)(ws + 192937984);
  unsigned short* Wqkv   = (unsigned short*)(ws + 260046848);
  float*          biasQ  = (float*)(ws + 266338304);
  float*          pooled = (float*)(ws + 266349824);
  int*            cntW   = (int*)(ws + 266472704);
  int*            idxW   = (int*)(ws + 266472832);

  const float scaleQ = 0.0322748612183951f;  // 1/sqrt(960)

  scan_mask<<<32, 256, 0, stream>>>(mask, idxW, cntW);
  cast_wqkv<<<2880, 256, 0, stream>>>(Wq, Wk, Wv, bq, bk, bv, Wqkv, biasQ, scaleQ);
  compact_x<<<dim3(256, 32), 256, 0, stream>>>(x, idxW, cntW, xc);

  gemm128<1><<<32 * 8 * 23, 256, 0, stream>>>(
      xc, Wqkv, 1024, 1024, biasQ, nullptr, Qb, Kb, Vt,
      8, 23, 15, 2880, 0, (size_t)1048576, 0, 0, cntW);

  attn_softmax<<<512, 512, 0, stream>>>(Qb, Kb, cntW, P);

  gemm128<2><<<8 * 8 * 32, 256, 0, stream>>>(
      P, Vt, 1024, 1024, nullptr, ctxb, nullptr, nullptr, nullptr,
      8, 8, 0, 960, 960, (size_t)1048576, (size_t)1048576, (size_t)983040, cntW);

  hipMemsetAsync(pooled, 0, 32 * 960 * 4, stream);
  ln_pool<<<dim3(32, 32), 256, 0, stream>>>(ctxb, x, idxW, cntW, lng, lnb, pooled);
  mlp_head<<<32, 256, 0, stream>>>(pooled, cntW, W1, b1, W2, b2, W3, b3, W4, b4, out);
}

// Round 10
// 503.127 us; speedup vs baseline: 1.5164x; 1.0226x over previous
//
#include <hip/hip_runtime.h>

// ---------------------------------------------------------------------------
// DeepProteinClassifier with mask-compaction + attn strip-skip.
//   scan_mask -> compact_x -> QKV gemm -> attn (strip-skip) -> PV gemm ->
//   LN+pool -> MLP.
// GEMM: m97-structure gemm128s — 128x128 tile, BK=32, SINGLE-buffered 16KB
// LDS (-> ~8 blocks/CU TLP), plain __syncthreads (compiler-managed waitcnt),
// (row>>1)&3 slot swizzle (0 bank conflicts at 64B rows).
// ---------------------------------------------------------------------------

#define DEVINL __device__ __forceinline__

typedef __attribute__((ext_vector_type(8))) short bf16x8;
typedef __attribute__((ext_vector_type(4))) float f32x4;
typedef __attribute__((ext_vector_type(4))) unsigned short u16x4;

DEVINL unsigned short f2bf(float f) {
  unsigned int u = __float_as_uint(f);
  u += 0x7FFFu + ((u >> 16) & 1u);  // round-to-nearest-even
  return (unsigned short)(u >> 16);
}

DEVINL float bf2f(unsigned short h) { return __uint_as_float(((unsigned int)h) << 16); }

DEVINL void gload_lds16(const void* g, void* l) {
  __builtin_amdgcn_global_load_lds((const __attribute__((address_space(1))) unsigned int*)g,
                                   (__attribute__((address_space(3))) unsigned int*)l,
                                   16, 0, 0);
}

#define MFMA16(a, b, c) __builtin_amdgcn_mfma_f32_16x16x32_bf16((a), (b), (c), 0, 0, 0)

// ---------------------------------------------------------------------------
// Per-b prefix scan of mask: idx[b][j] = s of j-th unmasked row; cnt[b].
// ---------------------------------------------------------------------------
__global__ __launch_bounds__(256) void scan_mask(
    const int* __restrict__ mask, int* __restrict__ idx, int* __restrict__ cnt) {
  __shared__ int ps[256];
  const int b = blockIdx.x, t = threadIdx.x;
  const int4 m = *(const int4*)(mask + b * 1024 + t * 4);
  const int s = (m.x != 0) + (m.y != 0) + (m.z != 0) + (m.w != 0);
  ps[t] = s;
  __syncthreads();
  for (int off = 1; off < 256; off <<= 1) {
    const int v = (t >= off) ? ps[t - off] : 0;
    __syncthreads();
    ps[t] += v;
    __syncthreads();
  }
  int pos = ps[t] - s;
  if (m.x) idx[b * 1024 + pos++] = t * 4 + 0;
  if (m.y) idx[b * 1024 + pos++] = t * 4 + 1;
  if (m.z) idx[b * 1024 + pos++] = t * 4 + 2;
  if (m.w) idx[b * 1024 + pos++] = t * 4 + 3;
  if (t == 255) cnt[b] = ps[255];
}

// ---------------------------------------------------------------------------
// Build Wqkv [3072][1024] bf16 + biasQKV[2880] f32 (Q pre-scaled).
// ---------------------------------------------------------------------------
__global__ __launch_bounds__(256) void cast_wqkv(
    const float* __restrict__ Wq, const float* __restrict__ Wk, const float* __restrict__ Wv,
    const float* __restrict__ bq, const float* __restrict__ bk, const float* __restrict__ bv,
    unsigned short* __restrict__ Wqkv, float* __restrict__ biasQ, float scaleQ) {
  const int r = blockIdx.x, t = threadIdx.x;
  const int seg = (r >= 1920) ? 2 : (r >= 960 ? 1 : 0);
  const int sr = r - seg * 960;
  const float* W = (seg == 0) ? Wq : (seg == 1) ? Wk : Wv;
  const float sc = (seg == 0) ? scaleQ : 1.0f;
  if (t < 240) {
    f32x4 v = *(const f32x4*)(W + (size_t)sr * 960 + t * 4);
    u16x4 o;
    o[0] = f2bf(v[0] * sc); o[1] = f2bf(v[1] * sc);
    o[2] = f2bf(v[2] * sc); o[3] = f2bf(v[3] * sc);
    *(u16x4*)(Wqkv + (size_t)r * 1024 + t * 4) = o;
  } else {
    u16x4 z = {};
    *(u16x4*)(Wqkv + (size_t)r * 1024 + 960 + (t - 240) * 4) = z;
  }
  if (t == 0) {
    const float* bb = (seg == 0) ? bq : (seg == 1) ? bk : bv;
    biasQ[r] = bb[sr] * sc;
  }
}

// ---------------------------------------------------------------------------
// Gather-compact-cast: xc[b][j] = bf16(x[b][idx[b][j]]) for j < cnt[b];
// zero rows j in [cnt, ceil128(cnt)); 1024 cols (960 data + 64 zero pad).
// ---------------------------------------------------------------------------
__global__ __launch_bounds__(256) void compact_x(
    const float* __restrict__ x, const int* __restrict__ idx, const int* __restrict__ cnt,
    unsigned short* __restrict__ xc) {
  const int b = blockIdx.y;
  const int j = blockIdx.x * 4 + (threadIdx.x >> 6);
  const int l = threadIdx.x & 63;
  const int cb = cnt[b];
  const int cbc = (cb + 127) & ~127;
  if (j >= cbc) return;
  unsigned short* o = xc + ((size_t)b * 1024 + j) * 1024 + l * 16;
  bf16x8 o0 = {}, o1 = {};
  if (j < cb && l < 60) {
    const int s = idx[b * 1024 + j];
    const float* g = x + ((size_t)b * 1024 + s) * 960 + l * 16;
    f32x4 v0 = *(const f32x4*)(g);
    f32x4 v1 = *(const f32x4*)(g + 4);
    f32x4 v2 = *(const f32x4*)(g + 8);
    f32x4 v3 = *(const f32x4*)(g + 12);
    o0[0] = (short)f2bf(v0[0]); o0[1] = (short)f2bf(v0[1]);
    o0[2] = (short)f2bf(v0[2]); o0[3] = (short)f2bf(v0[3]);
    o0[4] = (short)f2bf(v1[0]); o0[5] = (short)f2bf(v1[1]);
    o0[6] = (short)f2bf(v1[2]); o0[7] = (short)f2bf(v1[3]);
    o1[0] = (short)f2bf(v2[0]); o1[1] = (short)f2bf(v2[1]);
    o1[2] = (short)f2bf(v2[2]); o1[3] = (short)f2bf(v2[3]);
    o1[4] = (short)f2bf(v3[0]); o1[5] = (short)f2bf(v3[1]);
    o1[6] = (short)f2bf(v3[2]); o1[7] = (short)f2bf(v3[3]);
  }
  *(bf16x8*)(o) = o0;
  *(bf16x8*)(o + 8) = o1;
}

// ---------------------------------------------------------------------------
// gemm128s: 128x128 NT GEMM, m97 structure. BK=32, SINGLE 16KB LDS buffer,
// 4 waves (2x2), 64x64 out/wave. Per K-iter: sync; stage (4 gload_lds/thr);
// sync (compiler drains vmcnt); 8 ds_read_b128 + 16 MFMA.
// (row>>1)&3 slot swizzle on 64B rows: source-side + read-side (2-way = free).
// Per-b compaction via cntArr (early-exit tiles past cnt).
// MODE 1: QKV epilogue (bf16 +bias -> Qb/Kb/Vt-transposed), nkt fixed.
// MODE 2: bf16 out (PV -> ctx), nkt = ceil32(cnt[zb]) (P cols >= cnt are 0).
// Bijective XCD-chunked swizzle; n-tile fastest.
// ---------------------------------------------------------------------------
template <int MODE>
__global__ __launch_bounds__(256, 4) void gemm128s(
    const unsigned short* __restrict__ Ap, const unsigned short* __restrict__ Bp,
    int lda, int ldb, const float* __restrict__ bias,
    unsigned short* __restrict__ outC, unsigned short* __restrict__ outQ,
    unsigned short* __restrict__ outK, unsigned short* __restrict__ outV,
    int mTiles, int nTiles, int nktFixed, int ncols, int ldo,
    size_t aStride, size_t bStride, size_t oStride, const int* __restrict__ cntArr) {
  __shared__ unsigned short As[128 * 32];
  __shared__ unsigned short Bs[128 * 32];
  const int t = threadIdx.x, l = t & 63, w = t >> 6;
  const int wr = w >> 1, wc = w & 1;
  const int lq = l & 15, lh = l >> 4;

  const int nwg = (int)gridDim.x;
  const int flat = (int)blockIdx.x;
  const int q8 = nwg >> 3, r8 = nwg & 7, xcd = flat & 7;
  const int wgid = (xcd < r8 ? xcd * (q8 + 1) : r8 * (q8 + 1) + (xcd - r8) * q8) + (flat >> 3);
  const int pt = mTiles * nTiles;
  const int zb = wgid / pt;
  const int rm = wgid - zb * pt;
  const int mi = rm / nTiles;
  const int m0 = mi * 128;
  const int n0 = (rm - mi * nTiles) * 128;

  const int cb = cntArr[zb];
  if (m0 >= cb) return;
  const int nkt = (MODE == 2) ? ((cb + 31) >> 5) : nktFixed;

  const unsigned short* A = Ap + (size_t)zb * aStride + (size_t)m0 * lda;
  const unsigned short* B = Bp + (size_t)zb * bStride + (size_t)n0 * ldb;

  // stage one 128x32 operand slab: 2 rounds of 64 rows; per-wave 16 rows/round
  const int srow0 = w * 16 + (l >> 2);  // within-round row for this lane
  const int sg0 = l & 3;

  f32x4 acc[4][4] = {};
  for (int kt = 0; kt < nkt; ++kt) {
    const int d0 = kt * 32;
    __syncthreads();  // prior reads of As/Bs complete before overwrite
#pragma unroll
    for (int p = 0; p < 2; ++p) {
      const int row = p * 64 + srow0;
      const int sg = sg0 ^ ((row >> 1) & 3);
      gload_lds16(A + (size_t)row * lda + d0 + sg * 8,
                  (char*)As + (size_t)(p * 64 + w * 16) * 64);
      gload_lds16(B + (size_t)row * ldb + d0 + sg * 8,
                  (char*)Bs + (size_t)(p * 64 + w * 16) * 64);
    }
    __syncthreads();  // compiler inserts s_waitcnt vmcnt(0) before barrier
    bf16x8 aF[4], bF[4];
#pragma unroll
    for (int i = 0; i < 4; ++i) {
      const int rowA = 64 * wr + 16 * i + lq;
      aF[i] = *(const bf16x8*)(As + (size_t)rowA * 32 +
                               (size_t)(lh ^ ((rowA >> 1) & 3)) * 8);
      const int rowB = 64 * wc + 16 * i + lq;
      bF[i] = *(const bf16x8*)(Bs + (size_t)rowB * 32 +
                               (size_t)(lh ^ ((rowB >> 1) & 3)) * 8);
    }
#pragma unroll
    for (int i = 0; i < 4; ++i)
#pragma unroll
      for (int j = 0; j < 4; ++j) acc[i][j] = MFMA16(aF[i], bF[j], acc[i][j]);
  }

  // epilogue: C/D layout col = lane&15, row = (lane>>4)*4 + reg
  if (MODE == 2) {
#pragma unroll
    for (int j = 0; j < 4; ++j) {
      const int col = n0 + 64 * wc + 16 * j + lq;
      if (col >= ncols) continue;
#pragma unroll
      for (int i = 0; i < 4; ++i)
#pragma unroll
        for (int r = 0; r < 4; ++r) {
          const int row = m0 + 64 * wr + 16 * i + 4 * lh + r;
          outC[(size_t)zb * oStride + (size_t)row * ldo + col] = f2bf(acc[i][j][r]);
        }
    }
  } else {
#pragma unroll
    for (int j = 0; j < 4; ++j) {
      const int col = n0 + 64 * wc + 16 * j + lq;
      if (col >= ncols) continue;
      const int seg = (col >= 1920) ? 2 : (col >= 960 ? 1 : 0);
      const int dcol = col - seg * 960;
      const float bv = bias[col];
#pragma unroll
      for (int i = 0; i < 4; ++i)
#pragma unroll
        for (int r = 0; r < 4; ++r) {
          const int row = m0 + 64 * wr + 16 * i + 4 * lh + r;  // j within b
          const unsigned short v = f2bf(acc[i][j][r] + bv);
          if (seg == 0) outQ[((size_t)zb * 1024 + row) * 960 + dcol] = v;
          else if (seg == 1) outK[((size_t)zb * 1024 + row) * 960 + dcol] = v;
          else outV[((size_t)zb << 20) + ((size_t)dcol << 10) + row] = v;
        }
    }
  }
}

// ---------------------------------------------------------------------------
// Fused scores + masked softmax over COMPACTED rows, with STRIP-SKIP
// (unchanged from round 9).
// ---------------------------------------------------------------------------
__global__ __launch_bounds__(512, 2) void attn_softmax(
    const unsigned short* __restrict__ Qb, const unsigned short* __restrict__ Kb,
    const int* __restrict__ cnt, unsigned short* __restrict__ P) {
  __shared__ unsigned short Ks[2][1024 * 32];
  __shared__ unsigned short Qs[2][64 * 32];
  __shared__ float red[2][8][64];
  const int t = threadIdx.x, l = t & 63, w = t >> 6;
  const int flat = blockIdx.x;
  const int b = (flat & 7) * 4 + ((flat >> 3) >> 4);
  const int q0 = ((flat >> 3) & 15) * 64;
  const int cb = cnt[b];
  if (q0 >= cb) return;
  const int nks = (cb + 127) >> 7;
  const int lq = l & 15, lh = l >> 4;
  const size_t kbase = (size_t)b * 1024 * 960;
  const size_t qbase = ((size_t)b * 1024 + q0) * 960;
  const int lr = l >> 2, sg0 = l & 3;

#define STAGE(kkv, bufv)                                                      \
  {                                                                           \
    const int d0_ = (kkv) * 32;                                               \
    _Pragma("unroll") for (int i_ = 0; i_ < 8; ++i_) {                        \
      const int br_ = i_ * 128 + w * 16;                                      \
      const int kr_ = (i_ < nks) ? (br_ + lr) : (w * 16 + lr);                \
      const int sg_ = sg0 ^ ((kr_ >> 1) & 3);                                 \
      gload_lds16(Kb + kbase + (size_t)kr_ * 960 + d0_ + sg_ * 8,             \
                  (char*)Ks[(bufv)] + (size_t)br_ * 64);                      \
    }                                                                         \
    {                                                                         \
      const int qw_ = w & 3;                                                  \
      const int qr_ = qw_ * 16 + lr;                                          \
      const int sg_ = sg0 ^ ((qr_ >> 1) & 3);                                 \
      gload_lds16(Qb + qbase + (size_t)qr_ * 960 + d0_ + sg_ * 8,             \
                  (char*)Qs[(bufv)] + (size_t)(qw_ * 16) * 64);               \
    }                                                                         \
  }

  f32x4 acc[4][8] = {};
  STAGE(0, 0);
  int buf = 0;
  for (int kk = 0; kk < 30; ++kk) {
    if (kk < 29) {
      STAGE(kk + 1, buf ^ 1);
      asm volatile("s_waitcnt vmcnt(9)" ::: "memory");
    } else {
      asm volatile("s_waitcnt vmcnt(0)" ::: "memory");
    }
    __builtin_amdgcn_sched_barrier(0);
    __builtin_amdgcn_s_barrier();
    if (w < nks) {
      bf16x8 aF[4], bF[8];
#pragma unroll
      for (int i = 0; i < 4; ++i) {
        const int qr = 16 * i + lq;
        aF[i] = *(const bf16x8*)(Qs[buf] + qr * 32 + (lh ^ ((qr >> 1) & 3)) * 8);
      }
#pragma unroll
      for (int j = 0; j < 8; ++j) {
        const int kr = 128 * w + 16 * j + lq;
        bF[j] = *(const bf16x8*)(Ks[buf] + kr * 32 + (lh ^ ((kr >> 1) & 3)) * 8);
      }
#pragma unroll
      for (int i = 0; i < 4; ++i)
#pragma unroll
        for (int j = 0; j < 8; ++j) acc[i][j] = MFMA16(aF[i], bF[j], acc[i][j]);
    }
    __builtin_amdgcn_s_barrier();
    buf ^= 1;
  }
#undef STAGE

#pragma unroll
  for (int j = 0; j < 8; ++j) {
    const int k = 128 * w + 16 * j + lq;
    if (k >= cb) {
#pragma unroll
      for (int i = 0; i < 4; ++i)
#pragma unroll
        for (int r = 0; r < 4; ++r) acc[i][j][r] = -1e9f;
    }
  }

  float rmax[4][4];
#pragma unroll
  for (int i = 0; i < 4; ++i)
#pragma unroll
    for (int r = 0; r < 4; ++r) {
      float m = acc[i][0][r];
#pragma unroll
      for (int j = 1; j < 8; ++j) m = fmaxf(m, acc[i][j][r]);
      m = fmaxf(m, __shfl_xor(m, 1));
      m = fmaxf(m, __shfl_xor(m, 2));
      m = fmaxf(m, __shfl_xor(m, 4));
      m = fmaxf(m, __shfl_xor(m, 8));
      rmax[i][r] = m;
    }
  if (lq == 0) {
#pragma unroll
    for (int i = 0; i < 4; ++i)
#pragma unroll
      for (int r = 0; r < 4; ++r) red[0][w][16 * i + 4 * lh + r] = rmax[i][r];
  }
  __syncthreads();
#pragma unroll
  for (int i = 0; i < 4; ++i)
#pragma unroll
    for (int r = 0; r < 4; ++r) {
      const int rowi = 16 * i + 4 * lh + r;
      float m = red[0][0][rowi];
#pragma unroll
      for (int w2 = 1; w2 < 8; ++w2) m = fmaxf(m, red[0][w2][rowi]);
      rmax[i][r] = m;
    }

  float rsum[4][4];
#pragma unroll
  for (int i = 0; i < 4; ++i)
#pragma unroll
    for (int r = 0; r < 4; ++r) {
      float s = 0.f;
#pragma unroll
      for (int j = 0; j < 8; ++j) {
        const float e = __expf(acc[i][j][r] - rmax[i][r]);
        acc[i][j][r] = e;
        s += e;
      }
      s += __shfl_xor(s, 1); s += __shfl_xor(s, 2);
      s += __shfl_xor(s, 4); s += __shfl_xor(s, 8);
      rsum[i][r] = s;
    }
  if (lq == 0) {
#pragma unroll
    for (int i = 0; i < 4; ++i)
#pragma unroll
      for (int r = 0; r < 4; ++r) red[1][w][16 * i + 4 * lh + r] = rsum[i][r];
  }
  __syncthreads();

  if (w < nks) {
    const size_t pb = ((size_t)b << 20) + (size_t)q0 * 1024;
#pragma unroll
    for (int i = 0; i < 4; ++i)
#pragma unroll
      for (int r = 0; r < 4; ++r) {
        const int rowi = 16 * i + 4 * lh + r;
        float s = 0.f;
#pragma unroll
        for (int w2 = 0; w2 < 8; ++w2) s += red[1][w2][rowi];
        const float inv = 1.0f / s;
#pragma unroll
        for (int j = 0; j < 8; ++j) {
          const int col = 128 * w + 16 * j + lq;
          P[pb + (size_t)rowi * 1024 + col] = f2bf(acc[i][j][r] * inv);
        }
      }
  }
}

// ---------------------------------------------------------------------------
// Compacted LN+pool.
// ---------------------------------------------------------------------------
__global__ __launch_bounds__(256) void ln_pool(
    const unsigned short* __restrict__ ctxb, const float* __restrict__ x,
    const int* __restrict__ idx, const int* __restrict__ cnt,
    const float* __restrict__ g, const float* __restrict__ bta,
    float* __restrict__ pooled) {
  const int b = blockIdx.y, chunk = blockIdx.x;
  const int w = threadIdx.x >> 6, l = threadIdx.x & 63;
  const int cb = cnt[b];
  f32x4 gc[4], bc[4];
#pragma unroll
  for (int c = 0; c < 4; ++c) {
    const int i4 = c * 64 + l;
    if (i4 < 240) {
      gc[c] = *(const f32x4*)(g + i4 * 4);
      bc[c] = *(const f32x4*)(bta + i4 * 4);
    }
  }
  f32x4 accp[4] = {};
  for (int rr = 0; rr < 8; ++rr) {
    const int j = chunk * 32 + w * 8 + rr;
    if (j >= cb) continue;
    const int sidx = idx[b * 1024 + j];
    const size_t cbase = ((size_t)b * 1024 + j) * 960;
    const size_t xbase = ((size_t)b * 1024 + sidx) * 960;
    f32x4 h[4];
    float part = 0.f;
#pragma unroll
    for (int c = 0; c < 4; ++c) {
      const int i4 = c * 64 + l;
      if (i4 < 240) {
        u16x4 cv = *(const u16x4*)(ctxb + cbase + (size_t)i4 * 4);
        f32x4 xv = *(const f32x4*)(x + xbase + (size_t)i4 * 4);
        h[c][0] = bf2f(cv[0]) + xv[0];
        h[c][1] = bf2f(cv[1]) + xv[1];
        h[c][2] = bf2f(cv[2]) + xv[2];
        h[c][3] = bf2f(cv[3]) + xv[3];
        part += h[c][0] + h[c][1] + h[c][2] + h[c][3];
      } else {
        h[c] = 0;
      }
    }
#pragma unroll
    for (int o = 1; o < 64; o <<= 1) part += __shfl_xor(part, o);
    const float mu = part * (1.0f / 960.0f);
    float p2 = 0.f;
#pragma unroll
    for (int c = 0; c < 4; ++c) {
      if (c * 64 + l < 240) {
#pragma unroll
        for (int k2 = 0; k2 < 4; ++k2) {
          const float d = h[c][k2] - mu;
          p2 += d * d;
        }
      }
    }
#pragma unroll
    for (int o = 1; o < 64; o <<= 1) p2 += __shfl_xor(p2, o);
    const float rs = rsqrtf(p2 * (1.0f / 960.0f) + 1e-5f);
#pragma unroll
    for (int c = 0; c < 4; ++c) {
      if (c * 64 + l < 240) {
#pragma unroll
        for (int k2 = 0; k2 < 4; ++k2)
          accp[c][k2] += (h[c][k2] - mu) * rs * gc[c][k2] + bc[c][k2];
      }
    }
  }
#pragma unroll
  for (int c = 0; c < 4; ++c) {
    const int i4 = c * 64 + l;
    if (i4 < 240) {
#pragma unroll
      for (int k2 = 0; k2 < 4; ++k2) atomicAdd(&pooled[b * 960 + i4 * 4 + k2], accp[c][k2]);
    }
  }
}

// ---------------------------------------------------------------------------
// pooled/cnt -> 960-512-256-128-10 MLP fp32.
// ---------------------------------------------------------------------------
__global__ __launch_bounds__(256) void mlp_head(
    const float* __restrict__ pooled, const int* __restrict__ cnt,
    const float* __restrict__ W1, const float* __restrict__ b1,
    const float* __restrict__ W2, const float* __restrict__ b2,
    const float* __restrict__ W3, const float* __restrict__ b3,
    const float* __restrict__ W4, const float* __restrict__ b4, float* __restrict__ out) {
  __shared__ float h0[960], h1[512], h2[256], h3[128];
  const int b = blockIdx.x, t = threadIdx.x;
  const float inv = 1.0f / fmaxf((float)cnt[b], 1e-9f);
  for (int d = t; d < 960; d += 256) h0[d] = pooled[b * 960 + d] * inv;
  __syncthreads();
  for (int o = t; o < 512; o += 256) {
    float a = b1[o];
    const float* wr = W1 + (size_t)o * 960;
    for (int k = 0; k < 960; k += 4) {
      f32x4 wv = *(const f32x4*)(wr + k);
      f32x4 hv = *(const f32x4*)(h0 + k);
      a += wv[0] * hv[0] + wv[1] * hv[1] + wv[2] * hv[2] + wv[3] * hv[3];
    }
    h1[o] = fmaxf(a, 0.f);
  }
  __syncthreads();
  {
    float a = b2[t];
    const float* wr = W2 + (size_t)t * 512;
    for (int k = 0; k < 512; k += 4) {
      f32x4 wv = *(const f32x4*)(wr + k);
      f32x4 hv = *(const f32x4*)(h1 + k);
      a += wv[0] * hv[0] + wv[1] * hv[1] + wv[2] * hv[2] + wv[3] * hv[3];
    }
    h2[t] = fmaxf(a, 0.f);
  }
  __syncthreads();
  if (t < 128) {
    float a = b3[t];
    const float* wr = W3 + (size_t)t * 256;
    for (int k = 0; k < 256; k += 4) {
      f32x4 wv = *(const f32x4*)(wr + k);
      f32x4 hv = *(const f32x4*)(h2 + k);
      a += wv[0] * hv[0] + wv[1] * hv[1] + wv[2] * hv[2] + wv[3] * hv[3];
    }
    h3[t] = fmaxf(a, 0.f);
  }
  __syncthreads();
  if (t < 10) {
    float a = b4[t];
    const float* wr = W4 + (size_t)t * 128;
    for (int k = 0; k < 128; ++k) a += wr[k] * h3[k];
    out[b * 10 + t] = a;
  }
}

// ---------------------------------------------------------------------------
// Workspace layout identical to rounds 8/9.
// ---------------------------------------------------------------------------
extern "C" void kernel_launch(void* const* d_in, const int* in_sizes, int n_in,
                              void* d_out, int out_size, void* d_ws, size_t ws_size,
                              hipStream_t stream) {
  (void)in_sizes; (void)n_in; (void)out_size; (void)ws_size;
  const float* x    = (const float*)d_in[0];
  const int*   mask = (const int*)d_in[1];
  const float* Wq   = (const float*)d_in[2];
  const float* bq   = (const float*)d_in[3];
  const float* Wk   = (const float*)d_in[4];
  const float* bk   = (const float*)d_in[5];
  const float* Wv   = (const float*)d_in[6];
  const float* bv   = (const float*)d_in[7];
  const float* lng  = (const float*)d_in[8];
  const float* lnb  = (const float*)d_in[9];
  const float* W1   = (const float*)d_in[10];
  const float* b1   = (const float*)d_in[11];
  const float* W2   = (const float*)d_in[12];
  const float* b2   = (const float*)d_in[13];
  const float* W3   = (const float*)d_in[14];
  const float* b3   = (const float*)d_in[15];
  const float* W4   = (const float*)d_in[16];
  const float* b4   = (const float*)d_in[17];
  float* out = (float*)d_out;

  char* ws = (char*)d_ws;
  unsigned short* xc     = (unsigned short*)(ws);
  unsigned short* P      = (unsigned short*)(ws);
  unsigned short* Qb     = (unsigned short*)(ws + 67108864);
  unsigned short* Kb     = (unsigned short*)(ws + 130023424);
  unsigned short* ctxb   = (unsigned short*)(ws + 67108864);
  unsigned short* Vt     = (unsigned short*)(ws + 192937984);
  unsigned short* Wqkv   = (unsigned short*)(ws + 260046848);
  float*          biasQ  = (float*)(ws + 266338304);
  float*          pooled = (float*)(ws + 266349824);
  int*            cntW   = (int*)(ws + 266472704);
  int*            idxW   = (int*)(ws + 266472832);

  const float scaleQ = 0.0322748612183951f;  // 1/sqrt(960)

  scan_mask<<<32, 256, 0, stream>>>(mask, idxW, cntW);
  cast_wqkv<<<2880, 256, 0, stream>>>(Wq, Wk, Wv, bq, bk, bv, Wqkv, biasQ, scaleQ);
  compact_x<<<dim3(256, 32), 256, 0, stream>>>(x, idxW, cntW, xc);

  // fused QKV: per b, M = ceil128(cnt[b]) (early-exit), N = 2880, K = 960
  gemm128s<1><<<32 * 8 * 23, 256, 0, stream>>>(
      xc, Wqkv, 1024, 1024, biasQ, nullptr, Qb, Kb, Vt,
      8, 23, 30, 2880, 0, (size_t)1048576, 0, 0, cntW);

  attn_softmax<<<512, 512, 0, stream>>>(Qb, Kb, cntW, P);

  // ctx[b] = P[b] . Vt[b]^T : M = ceil128(cnt), N=960, K = ceil32(cnt)
  gemm128s<2><<<8 * 8 * 32, 256, 0, stream>>>(
      P, Vt, 1024, 1024, nullptr, ctxb, nullptr, nullptr, nullptr,
      8, 8, 0, 960, 960, (size_t)1048576, (size_t)1048576, (size_t)983040, cntW);

  hipMemsetAsync(pooled, 0, 32 * 960 * 4, stream);
  ln_pool<<<dim3(32, 32), 256, 0, stream>>>(ctxb, x, idxW, cntW, lng, lnb, pooled);
  mlp_head<<<32, 256, 0, stream>>>(pooled, cntW, W1, b1, W2, b2, W3, b3, W4, b4, out);
}

// Round 11
// 457.346 us; speedup vs baseline: 1.6682x; 1.1001x over previous
//
#include <hip/hip_runtime.h>

// ---------------------------------------------------------------------------
// DeepProteinClassifier with mask-compaction + attn strip-skip (NKS-templated
// staging: only live k-strips are staged; vmcnt ledger per-template).
//   scan_mask -> compact_x -> QKV gemm -> attn -> PV gemm -> LN+pool -> MLP.
// GEMM: m97-structure gemm128s (BK=32, single 16KB LDS, ~8 blocks/CU TLP).
// ---------------------------------------------------------------------------

#define DEVINL __device__ __forceinline__

typedef __attribute__((ext_vector_type(8))) short bf16x8;
typedef __attribute__((ext_vector_type(4))) float f32x4;
typedef __attribute__((ext_vector_type(4))) unsigned short u16x4;

DEVINL unsigned short f2bf(float f) {
  unsigned int u = __float_as_uint(f);
  u += 0x7FFFu + ((u >> 16) & 1u);  // round-to-nearest-even
  return (unsigned short)(u >> 16);
}

DEVINL float bf2f(unsigned short h) { return __uint_as_float(((unsigned int)h) << 16); }

DEVINL void gload_lds16(const void* g, void* l) {
  __builtin_amdgcn_global_load_lds((const __attribute__((address_space(1))) unsigned int*)g,
                                   (__attribute__((address_space(3))) unsigned int*)l,
                                   16, 0, 0);
}

#define MFMA16(a, b, c) __builtin_amdgcn_mfma_f32_16x16x32_bf16((a), (b), (c), 0, 0, 0)

// ---------------------------------------------------------------------------
// Per-b prefix scan of mask: idx[b][j] = s of j-th unmasked row; cnt[b].
// ---------------------------------------------------------------------------
__global__ __launch_bounds__(256) void scan_mask(
    const int* __restrict__ mask, int* __restrict__ idx, int* __restrict__ cnt) {
  __shared__ int ps[256];
  const int b = blockIdx.x, t = threadIdx.x;
  const int4 m = *(const int4*)(mask + b * 1024 + t * 4);
  const int s = (m.x != 0) + (m.y != 0) + (m.z != 0) + (m.w != 0);
  ps[t] = s;
  __syncthreads();
  for (int off = 1; off < 256; off <<= 1) {
    const int v = (t >= off) ? ps[t - off] : 0;
    __syncthreads();
    ps[t] += v;
    __syncthreads();
  }
  int pos = ps[t] - s;
  if (m.x) idx[b * 1024 + pos++] = t * 4 + 0;
  if (m.y) idx[b * 1024 + pos++] = t * 4 + 1;
  if (m.z) idx[b * 1024 + pos++] = t * 4 + 2;
  if (m.w) idx[b * 1024 + pos++] = t * 4 + 3;
  if (t == 255) cnt[b] = ps[255];
}

// ---------------------------------------------------------------------------
// Build Wqkv [3072][1024] bf16 + biasQKV[2880] f32 (Q pre-scaled).
// ---------------------------------------------------------------------------
__global__ __launch_bounds__(256) void cast_wqkv(
    const float* __restrict__ Wq, const float* __restrict__ Wk, const float* __restrict__ Wv,
    const float* __restrict__ bq, const float* __restrict__ bk, const float* __restrict__ bv,
    unsigned short* __restrict__ Wqkv, float* __restrict__ biasQ, float scaleQ) {
  const int r = blockIdx.x, t = threadIdx.x;
  const int seg = (r >= 1920) ? 2 : (r >= 960 ? 1 : 0);
  const int sr = r - seg * 960;
  const float* W = (seg == 0) ? Wq : (seg == 1) ? Wk : Wv;
  const float sc = (seg == 0) ? scaleQ : 1.0f;
  if (t < 240) {
    f32x4 v = *(const f32x4*)(W + (size_t)sr * 960 + t * 4);
    u16x4 o;
    o[0] = f2bf(v[0] * sc); o[1] = f2bf(v[1] * sc);
    o[2] = f2bf(v[2] * sc); o[3] = f2bf(v[3] * sc);
    *(u16x4*)(Wqkv + (size_t)r * 1024 + t * 4) = o;
  } else {
    u16x4 z = {};
    *(u16x4*)(Wqkv + (size_t)r * 1024 + 960 + (t - 240) * 4) = z;
  }
  if (t == 0) {
    const float* bb = (seg == 0) ? bq : (seg == 1) ? bk : bv;
    biasQ[r] = bb[sr] * sc;
  }
}

// ---------------------------------------------------------------------------
// Gather-compact-cast: xc[b][j] = bf16(x[b][idx[b][j]]) for j < cnt[b];
// zero rows j in [cnt, ceil128(cnt)); 1024 cols (960 data + 64 zero pad).
// ---------------------------------------------------------------------------
__global__ __launch_bounds__(256) void compact_x(
    const float* __restrict__ x, const int* __restrict__ idx, const int* __restrict__ cnt,
    unsigned short* __restrict__ xc) {
  const int b = blockIdx.y;
  const int j = blockIdx.x * 4 + (threadIdx.x >> 6);
  const int l = threadIdx.x & 63;
  const int cb = cnt[b];
  const int cbc = (cb + 127) & ~127;
  if (j >= cbc) return;
  unsigned short* o = xc + ((size_t)b * 1024 + j) * 1024 + l * 16;
  bf16x8 o0 = {}, o1 = {};
  if (j < cb && l < 60) {
    const int s = idx[b * 1024 + j];
    const float* g = x + ((size_t)b * 1024 + s) * 960 + l * 16;
    f32x4 v0 = *(const f32x4*)(g);
    f32x4 v1 = *(const f32x4*)(g + 4);
    f32x4 v2 = *(const f32x4*)(g + 8);
    f32x4 v3 = *(const f32x4*)(g + 12);
    o0[0] = (short)f2bf(v0[0]); o0[1] = (short)f2bf(v0[1]);
    o0[2] = (short)f2bf(v0[2]); o0[3] = (short)f2bf(v0[3]);
    o0[4] = (short)f2bf(v1[0]); o0[5] = (short)f2bf(v1[1]);
    o0[6] = (short)f2bf(v1[2]); o0[7] = (short)f2bf(v1[3]);
    o1[0] = (short)f2bf(v2[0]); o1[1] = (short)f2bf(v2[1]);
    o1[2] = (short)f2bf(v2[2]); o1[3] = (short)f2bf(v2[3]);
    o1[4] = (short)f2bf(v3[0]); o1[5] = (short)f2bf(v3[1]);
    o1[6] = (short)f2bf(v3[2]); o1[7] = (short)f2bf(v3[3]);
  }
  *(bf16x8*)(o) = o0;
  *(bf16x8*)(o + 8) = o1;
}

// ---------------------------------------------------------------------------
// gemm128s: 128x128 NT GEMM, m97 structure (BK=32, single 16KB LDS, 4 waves,
// plain __syncthreads). (row>>1)&3 slot swizzle. Per-b compaction via cntArr.
// MODE 1: QKV epilogue (V-stores merged to u16x4).  MODE 2: bf16 out.
// ---------------------------------------------------------------------------
template <int MODE>
__global__ __launch_bounds__(256, 4) void gemm128s(
    const unsigned short* __restrict__ Ap, const unsigned short* __restrict__ Bp,
    int lda, int ldb, const float* __restrict__ bias,
    unsigned short* __restrict__ outC, unsigned short* __restrict__ outQ,
    unsigned short* __restrict__ outK, unsigned short* __restrict__ outV,
    int mTiles, int nTiles, int nktFixed, int ncols, int ldo,
    size_t aStride, size_t bStride, size_t oStride, const int* __restrict__ cntArr) {
  __shared__ unsigned short As[128 * 32];
  __shared__ unsigned short Bs[128 * 32];
  const int t = threadIdx.x, l = t & 63, w = t >> 6;
  const int wr = w >> 1, wc = w & 1;
  const int lq = l & 15, lh = l >> 4;

  const int nwg = (int)gridDim.x;
  const int flat = (int)blockIdx.x;
  const int q8 = nwg >> 3, r8 = nwg & 7, xcd = flat & 7;
  const int wgid = (xcd < r8 ? xcd * (q8 + 1) : r8 * (q8 + 1) + (xcd - r8) * q8) + (flat >> 3);
  const int pt = mTiles * nTiles;
  const int zb = wgid / pt;
  const int rm = wgid - zb * pt;
  const int mi = rm / nTiles;
  const int m0 = mi * 128;
  const int n0 = (rm - mi * nTiles) * 128;

  const int cb = cntArr[zb];
  if (m0 >= cb) return;
  const int nkt = (MODE == 2) ? ((cb + 31) >> 5) : nktFixed;

  const unsigned short* A = Ap + (size_t)zb * aStride + (size_t)m0 * lda;
  const unsigned short* B = Bp + (size_t)zb * bStride + (size_t)n0 * ldb;

  const int srow0 = w * 16 + (l >> 2);
  const int sg0 = l & 3;

  f32x4 acc[4][4] = {};
  for (int kt = 0; kt < nkt; ++kt) {
    const int d0 = kt * 32;
    __syncthreads();
#pragma unroll
    for (int p = 0; p < 2; ++p) {
      const int row = p * 64 + srow0;
      const int sg = sg0 ^ ((row >> 1) & 3);
      gload_lds16(A + (size_t)row * lda + d0 + sg * 8,
                  (char*)As + (size_t)(p * 64 + w * 16) * 64);
      gload_lds16(B + (size_t)row * ldb + d0 + sg * 8,
                  (char*)Bs + (size_t)(p * 64 + w * 16) * 64);
    }
    __syncthreads();
    bf16x8 aF[4], bF[4];
#pragma unroll
    for (int i = 0; i < 4; ++i) {
      const int rowA = 64 * wr + 16 * i + lq;
      aF[i] = *(const bf16x8*)(As + (size_t)rowA * 32 +
                               (size_t)(lh ^ ((rowA >> 1) & 3)) * 8);
      const int rowB = 64 * wc + 16 * i + lq;
      bF[i] = *(const bf16x8*)(Bs + (size_t)rowB * 32 +
                               (size_t)(lh ^ ((rowB >> 1) & 3)) * 8);
    }
#pragma unroll
    for (int i = 0; i < 4; ++i)
#pragma unroll
      for (int j = 0; j < 4; ++j) acc[i][j] = MFMA16(aF[i], bF[j], acc[i][j]);
  }

  // epilogue: C/D layout col = lane&15, row = (lane>>4)*4 + reg
  if (MODE == 2) {
#pragma unroll
    for (int j = 0; j < 4; ++j) {
      const int col = n0 + 64 * wc + 16 * j + lq;
      if (col >= ncols) continue;
#pragma unroll
      for (int i = 0; i < 4; ++i)
#pragma unroll
        for (int r = 0; r < 4; ++r) {
          const int row = m0 + 64 * wr + 16 * i + 4 * lh + r;
          outC[(size_t)zb * oStride + (size_t)row * ldo + col] = f2bf(acc[i][j][r]);
        }
    }
  } else {
#pragma unroll
    for (int j = 0; j < 4; ++j) {
      const int col = n0 + 64 * wc + 16 * j + lq;
      if (col >= ncols) continue;
      const int seg = (col >= 1920) ? 2 : (col >= 960 ? 1 : 0);
      const int dcol = col - seg * 960;
      const float bv = bias[col];
      if (seg == 2) {  // V: rows r=0..3 are consecutive in Vt -> one u16x4
#pragma unroll
        for (int i = 0; i < 4; ++i) {
          const int row = m0 + 64 * wr + 16 * i + 4 * lh;  // j within b
          u16x4 v4;
          v4[0] = f2bf(acc[i][j][0] + bv);
          v4[1] = f2bf(acc[i][j][1] + bv);
          v4[2] = f2bf(acc[i][j][2] + bv);
          v4[3] = f2bf(acc[i][j][3] + bv);
          *(u16x4*)(outV + ((size_t)zb << 20) + ((size_t)dcol << 10) + row) = v4;
        }
      } else {
#pragma unroll
        for (int i = 0; i < 4; ++i)
#pragma unroll
          for (int r = 0; r < 4; ++r) {
            const int row = m0 + 64 * wr + 16 * i + 4 * lh + r;
            const unsigned short v = f2bf(acc[i][j][r] + bv);
            if (seg == 0) outQ[((size_t)zb * 1024 + row) * 960 + dcol] = v;
            else outK[((size_t)zb * 1024 + row) * 960 + dcol] = v;
          }
      }
    }
  }
}

// ---------------------------------------------------------------------------
// NKS-templated attn K-loop. Specialized NKS in {3,4,5,6}: stage exactly NKS
// strips + 1 Q per wave, vmcnt(NKS+1). NKS==8 is the generic dummy-load
// fallback (stages 8 strips, dead ones duplicate strip 0; vmcnt(9)).
// ---------------------------------------------------------------------------
template <int NKS>
DEVINL void attn_kloop(const unsigned short* __restrict__ Kp,
                       const unsigned short* __restrict__ Qp,
                       unsigned short (*Ks)[1024 * 32], unsigned short (*Qs)[64 * 32],
                       int w, int lr, int sg0, int lq, int lh, int nks_rt,
                       f32x4 (&acc)[4][8]) {
#define STG(kkv, bufv)                                                        \
  {                                                                           \
    const int d0_ = (kkv) * 32;                                               \
    _Pragma("unroll") for (int i_ = 0; i_ < NKS; ++i_) {                      \
      const int br_ = i_ * 128 + w * 16;                                      \
      const int kr_ = (NKS == 8) ? ((i_ < nks_rt) ? (br_ + lr) : (w * 16 + lr)) \
                                 : (br_ + lr);                                \
      const int sg_ = sg0 ^ ((kr_ >> 1) & 3);                                 \
      gload_lds16(Kp + (size_t)kr_ * 960 + d0_ + sg_ * 8,                     \
                  (char*)Ks[(bufv)] + (size_t)br_ * 64);                      \
    }                                                                         \
    {                                                                         \
      const int qw_ = w & 3;                                                  \
      const int qr_ = qw_ * 16 + lr;                                          \
      const int sg_ = sg0 ^ ((qr_ >> 1) & 3);                                 \
      gload_lds16(Qp + (size_t)qr_ * 960 + d0_ + sg_ * 8,                     \
                  (char*)Qs[(bufv)] + (size_t)(qw_ * 16) * 64);               \
    }                                                                         \
  }
  STG(0, 0);
  int buf = 0;
  const int gate = (NKS == 8) ? nks_rt : NKS;
  for (int kk = 0; kk < 30; ++kk) {
    if (kk < 29) {
      STG(kk + 1, buf ^ 1);
      if constexpr (NKS == 3)      asm volatile("s_waitcnt vmcnt(4)" ::: "memory");
      else if constexpr (NKS == 4) asm volatile("s_waitcnt vmcnt(5)" ::: "memory");
      else if constexpr (NKS == 5) asm volatile("s_waitcnt vmcnt(6)" ::: "memory");
      else if constexpr (NKS == 6) asm volatile("s_waitcnt vmcnt(7)" ::: "memory");
      else                         asm volatile("s_waitcnt vmcnt(9)" ::: "memory");
    } else {
      asm volatile("s_waitcnt vmcnt(0)" ::: "memory");
    }
    __builtin_amdgcn_sched_barrier(0);
    __builtin_amdgcn_s_barrier();
    if (w < gate) {
      bf16x8 aF[4], bF[8];
#pragma unroll
      for (int i = 0; i < 4; ++i) {
        const int qr = 16 * i + lq;
        aF[i] = *(const bf16x8*)(Qs[buf] + qr * 32 + (lh ^ ((qr >> 1) & 3)) * 8);
      }
#pragma unroll
      for (int j = 0; j < 8; ++j) {
        const int kr = 128 * w + 16 * j + lq;
        bF[j] = *(const bf16x8*)(Ks[buf] + kr * 32 + (lh ^ ((kr >> 1) & 3)) * 8);
      }
#pragma unroll
      for (int i = 0; i < 4; ++i)
#pragma unroll
        for (int j = 0; j < 8; ++j) acc[i][j] = MFMA16(aF[i], bF[j], acc[i][j]);
    }
    __builtin_amdgcn_s_barrier();
    buf ^= 1;
  }
#undef STG
}

// ---------------------------------------------------------------------------
// Fused scores + masked softmax over COMPACTED rows, strip-skip + NKS staging.
// ---------------------------------------------------------------------------
__global__ __launch_bounds__(512, 2) void attn_softmax(
    const unsigned short* __restrict__ Qb, const unsigned short* __restrict__ Kb,
    const int* __restrict__ cnt, unsigned short* __restrict__ P) {
  __shared__ unsigned short Ks[2][1024 * 32];
  __shared__ unsigned short Qs[2][64 * 32];
  __shared__ float red[2][8][64];
  const int t = threadIdx.x, l = t & 63, w = t >> 6;
  const int flat = blockIdx.x;
  const int b = (flat & 7) * 4 + ((flat >> 3) >> 4);
  const int q0 = ((flat >> 3) & 15) * 64;
  const int cb = cnt[b];
  if (q0 >= cb) return;
  const int nks = (cb + 127) >> 7;
  const int lq = l & 15, lh = l >> 4;
  const unsigned short* Kp = Kb + (size_t)b * 1024 * 960;
  const unsigned short* Qp = Qb + ((size_t)b * 1024 + q0) * 960;
  const int lr = l >> 2, sg0 = l & 3;

  f32x4 acc[4][8] = {};
  if (nks == 4)      attn_kloop<4>(Kp, Qp, Ks, Qs, w, lr, sg0, lq, lh, nks, acc);
  else if (nks == 5) attn_kloop<5>(Kp, Qp, Ks, Qs, w, lr, sg0, lq, lh, nks, acc);
  else if (nks == 3) attn_kloop<3>(Kp, Qp, Ks, Qs, w, lr, sg0, lq, lh, nks, acc);
  else if (nks == 6) attn_kloop<6>(Kp, Qp, Ks, Qs, w, lr, sg0, lq, lh, nks, acc);
  else               attn_kloop<8>(Kp, Qp, Ks, Qs, w, lr, sg0, lq, lh, nks, acc);

  // compacted cols >= cnt -> -1e9 (covers dead waves entirely: acc was 0)
#pragma unroll
  for (int j = 0; j < 8; ++j) {
    const int k = 128 * w + 16 * j + lq;
    if (k >= cb) {
#pragma unroll
      for (int i = 0; i < 4; ++i)
#pragma unroll
        for (int r = 0; r < 4; ++r) acc[i][j][r] = -1e9f;
    }
  }

  float rmax[4][4];
#pragma unroll
  for (int i = 0; i < 4; ++i)
#pragma unroll
    for (int r = 0; r < 4; ++r) {
      float m = acc[i][0][r];
#pragma unroll
      for (int j = 1; j < 8; ++j) m = fmaxf(m, acc[i][j][r]);
      m = fmaxf(m, __shfl_xor(m, 1));
      m = fmaxf(m, __shfl_xor(m, 2));
      m = fmaxf(m, __shfl_xor(m, 4));
      m = fmaxf(m, __shfl_xor(m, 8));
      rmax[i][r] = m;
    }
  if (lq == 0) {
#pragma unroll
    for (int i = 0; i < 4; ++i)
#pragma unroll
      for (int r = 0; r < 4; ++r) red[0][w][16 * i + 4 * lh + r] = rmax[i][r];
  }
  __syncthreads();
#pragma unroll
  for (int i = 0; i < 4; ++i)
#pragma unroll
    for (int r = 0; r < 4; ++r) {
      const int rowi = 16 * i + 4 * lh + r;
      float m = red[0][0][rowi];
#pragma unroll
      for (int w2 = 1; w2 < 8; ++w2) m = fmaxf(m, red[0][w2][rowi]);
      rmax[i][r] = m;
    }

  float rsum[4][4];
#pragma unroll
  for (int i = 0; i < 4; ++i)
#pragma unroll
    for (int r = 0; r < 4; ++r) {
      float s = 0.f;
#pragma unroll
      for (int j = 0; j < 8; ++j) {
        const float e = __expf(acc[i][j][r] - rmax[i][r]);
        acc[i][j][r] = e;
        s += e;
      }
      s += __shfl_xor(s, 1); s += __shfl_xor(s, 2);
      s += __shfl_xor(s, 4); s += __shfl_xor(s, 8);
      rsum[i][r] = s;
    }
  if (lq == 0) {
#pragma unroll
    for (int i = 0; i < 4; ++i)
#pragma unroll
      for (int r = 0; r < 4; ++r) red[1][w][16 * i + 4 * lh + r] = rsum[i][r];
  }
  __syncthreads();

  if (w < nks) {
    const size_t pb = ((size_t)b << 20) + (size_t)q0 * 1024;
#pragma unroll
    for (int i = 0; i < 4; ++i)
#pragma unroll
      for (int r = 0; r < 4; ++r) {
        const int rowi = 16 * i + 4 * lh + r;
        float s = 0.f;
#pragma unroll
        for (int w2 = 0; w2 < 8; ++w2) s += red[1][w2][rowi];
        const float inv = 1.0f / s;
#pragma unroll
        for (int j = 0; j < 8; ++j) {
          const int col = 128 * w + 16 * j + lq;
          P[pb + (size_t)rowi * 1024 + col] = f2bf(acc[i][j][r] * inv);
        }
      }
  }
}

// ---------------------------------------------------------------------------
// Compacted LN+pool.
// ---------------------------------------------------------------------------
__global__ __launch_bounds__(256) void ln_pool(
    const unsigned short* __restrict__ ctxb, const float* __restrict__ x,
    const int* __restrict__ idx, const int* __restrict__ cnt,
    const float* __restrict__ g, const float* __restrict__ bta,
    float* __restrict__ pooled) {
  const int b = blockIdx.y, chunk = blockIdx.x;
  const int w = threadIdx.x >> 6, l = threadIdx.x & 63;
  const int cb = cnt[b];
  f32x4 gc[4], bc[4];
#pragma unroll
  for (int c = 0; c < 4; ++c) {
    const int i4 = c * 64 + l;
    if (i4 < 240) {
      gc[c] = *(const f32x4*)(g + i4 * 4);
      bc[c] = *(const f32x4*)(bta + i4 * 4);
    }
  }
  f32x4 accp[4] = {};
  for (int rr = 0; rr < 8; ++rr) {
    const int j = chunk * 32 + w * 8 + rr;
    if (j >= cb) continue;
    const int sidx = idx[b * 1024 + j];
    const size_t cbase = ((size_t)b * 1024 + j) * 960;
    const size_t xbase = ((size_t)b * 1024 + sidx) * 960;
    f32x4 h[4];
    float part = 0.f;
#pragma unroll
    for (int c = 0; c < 4; ++c) {
      const int i4 = c * 64 + l;
      if (i4 < 240) {
        u16x4 cv = *(const u16x4*)(ctxb + cbase + (size_t)i4 * 4);
        f32x4 xv = *(const f32x4*)(x + xbase + (size_t)i4 * 4);
        h[c][0] = bf2f(cv[0]) + xv[0];
        h[c][1] = bf2f(cv[1]) + xv[1];
        h[c][2] = bf2f(cv[2]) + xv[2];
        h[c][3] = bf2f(cv[3]) + xv[3];
        part += h[c][0] + h[c][1] + h[c][2] + h[c][3];
      } else {
        h[c] = 0;
      }
    }
#pragma unroll
    for (int o = 1; o < 64; o <<= 1) part += __shfl_xor(part, o);
    const float mu = part * (1.0f / 960.0f);
    float p2 = 0.f;
#pragma unroll
    for (int c = 0; c < 4; ++c) {
      if (c * 64 + l < 240) {
#pragma unroll
        for (int k2 = 0; k2 < 4; ++k2) {
          const float d = h[c][k2] - mu;
          p2 += d * d;
        }
      }
    }
#pragma unroll
    for (int o = 1; o < 64; o <<= 1) p2 += __shfl_xor(p2, o);
    const float rs = rsqrtf(p2 * (1.0f / 960.0f) + 1e-5f);
#pragma unroll
    for (int c = 0; c < 4; ++c) {
      if (c * 64 + l < 240) {
#pragma unroll
        for (int k2 = 0; k2 < 4; ++k2)
          accp[c][k2] += (h[c][k2] - mu) * rs * gc[c][k2] + bc[c][k2];
      }
    }
  }
#pragma unroll
  for (int c = 0; c < 4; ++c) {
    const int i4 = c * 64 + l;
    if (i4 < 240) {
#pragma unroll
      for (int k2 = 0; k2 < 4; ++k2) atomicAdd(&pooled[b * 960 + i4 * 4 + k2], accp[c][k2]);
    }
  }
}

// ---------------------------------------------------------------------------
// pooled/cnt -> 960-512-256-128-10 MLP fp32.
// ---------------------------------------------------------------------------
__global__ __launch_bounds__(256) void mlp_head(
    const float* __restrict__ pooled, const int* __restrict__ cnt,
    const float* __restrict__ W1, const float* __restrict__ b1,
    const float* __restrict__ W2, const float* __restrict__ b2,
    const float* __restrict__ W3, const float* __restrict__ b3,
    const float* __restrict__ W4, const float* __restrict__ b4, float* __restrict__ out) {
  __shared__ float h0[960], h1[512], h2[256], h3[128];
  const int b = blockIdx.x, t = threadIdx.x;
  const float inv = 1.0f / fmaxf((float)cnt[b], 1e-9f);
  for (int d = t; d < 960; d += 256) h0[d] = pooled[b * 960 + d] * inv;
  __syncthreads();
  for (int o = t; o < 512; o += 256) {
    float a = b1[o];
    const float* wr = W1 + (size_t)o * 960;
    for (int k = 0; k < 960; k += 4) {
      f32x4 wv = *(const f32x4*)(wr + k);
      f32x4 hv = *(const f32x4*)(h0 + k);
      a += wv[0] * hv[0] + wv[1] * hv[1] + wv[2] * hv[2] + wv[3] * hv[3];
    }
    h1[o] = fmaxf(a, 0.f);
  }
  __syncthreads();
  {
    float a = b2[t];
    const float* wr = W2 + (size_t)t * 512;
    for (int k = 0; k < 512; k += 4) {
      f32x4 wv = *(const f32x4*)(wr + k);
      f32x4 hv = *(const f32x4*)(h1 + k);
      a += wv[0] * hv[0] + wv[1] * hv[1] + wv[2] * hv[2] + wv[3] * hv[3];
    }
    h2[t] = fmaxf(a, 0.f);
  }
  __syncthreads();
  if (t < 128) {
    float a = b3[t];
    const float* wr = W3 + (size_t)t * 256;
    for (int k = 0; k < 256; k += 4) {
      f32x4 wv = *(const f32x4*)(wr + k);
      f32x4 hv = *(const f32x4*)(h2 + k);
      a += wv[0] * hv[0] + wv[1] * hv[1] + wv[2] * hv[2] + wv[3] * hv[3];
    }
    h3[t] = fmaxf(a, 0.f);
  }
  __syncthreads();
  if (t < 10) {
    float a = b4[t];
    const float* wr = W4 + (size_t)t * 128;
    for (int k = 0; k < 128; ++k) a += wr[k] * h3[k];
    out[b * 10 + t] = a;
  }
}

// ---------------------------------------------------------------------------
// Workspace layout identical to rounds 8-10.
// ---------------------------------------------------------------------------
extern "C" void kernel_launch(void* const* d_in, const int* in_sizes, int n_in,
                              void* d_out, int out_size, void* d_ws, size_t ws_size,
                              hipStream_t stream) {
  (void)in_sizes; (void)n_in; (void)out_size; (void)ws_size;
  const float* x    = (const float*)d_in[0];
  const int*   mask = (const int*)d_in[1];
  const float* Wq   = (const float*)d_in[2];
  const float* bq   = (const float*)d_in[3];
  const float* Wk   = (const float*)d_in[4];
  const float* bk   = (const float*)d_in[5];
  const float* Wv   = (const float*)d_in[6];
  const float* bv   = (const float*)d_in[7];
  const float* lng  = (const float*)d_in[8];
  const float* lnb  = (const float*)d_in[9];
  const float* W1   = (const float*)d_in[10];
  const float* b1   = (const float*)d_in[11];
  const float* W2   = (const float*)d_in[12];
  const float* b2   = (const float*)d_in[13];
  const float* W3   = (const float*)d_in[14];
  const float* b3   = (const float*)d_in[15];
  const float* W4   = (const float*)d_in[16];
  const float* b4   = (const float*)d_in[17];
  float* out = (float*)d_out;

  char* ws = (char*)d_ws;
  unsigned short* xc     = (unsigned short*)(ws);
  unsigned short* P      = (unsigned short*)(ws);
  unsigned short* Qb     = (unsigned short*)(ws + 67108864);
  unsigned short* Kb     = (unsigned short*)(ws + 130023424);
  unsigned short* ctxb   = (unsigned short*)(ws + 67108864);
  unsigned short* Vt     = (unsigned short*)(ws + 192937984);
  unsigned short* Wqkv   = (unsigned short*)(ws + 260046848);
  float*          biasQ  = (float*)(ws + 266338304);
  float*          pooled = (float*)(ws + 266349824);
  int*            cntW   = (int*)(ws + 266472704);
  int*            idxW   = (int*)(ws + 266472832);

  const float scaleQ = 0.0322748612183951f;  // 1/sqrt(960)

  scan_mask<<<32, 256, 0, stream>>>(mask, idxW, cntW);
  cast_wqkv<<<2880, 256, 0, stream>>>(Wq, Wk, Wv, bq, bk, bv, Wqkv, biasQ, scaleQ);
  compact_x<<<dim3(256, 32), 256, 0, stream>>>(x, idxW, cntW, xc);

  // fused QKV: per b, M = ceil128(cnt[b]) (early-exit), N = 2880, K = 960
  gemm128s<1><<<32 * 8 * 23, 256, 0, stream>>>(
      xc, Wqkv, 1024, 1024, biasQ, nullptr, Qb, Kb, Vt,
      8, 23, 30, 2880, 0, (size_t)1048576, 0, 0, cntW);

  attn_softmax<<<512, 512, 0, stream>>>(Qb, Kb, cntW, P);

  // ctx[b] = P[b] . Vt[b]^T : M = ceil128(cnt), N=960, K = ceil32(cnt)
  gemm128s<2><<<8 * 8 * 32, 256, 0, stream>>>(
      P, Vt, 1024, 1024, nullptr, ctxb, nullptr, nullptr, nullptr,
      8, 8, 0, 960, 960, (size_t)1048576, (size_t)1048576, (size_t)983040, cntW);

  hipMemsetAsync(pooled, 0, 32 * 960 * 4, stream);
  ln_pool<<<dim3(32, 32), 256, 0, stream>>>(ctxb, x, idxW, cntW, lng, lnb, pooled);
  mlp_head<<<32, 256, 0, stream>>>(pooled, cntW, W1, b1, W2, b2, W3, b3, W4, b4, out);
}